// Round 10
// baseline (436.269 us; speedup 1.0000x reference)
//
#include <hip/hip_runtime.h>

// ---------- types ----------
typedef float f4 __attribute__((ext_vector_type(4)));
typedef unsigned short us4 __attribute__((ext_vector_type(4)));
typedef unsigned short us8 __attribute__((ext_vector_type(8)));
typedef __bf16 bf16x8 __attribute__((ext_vector_type(8)));
typedef float f32x4 __attribute__((ext_vector_type(4)));
typedef _Float16 h8 __attribute__((ext_vector_type(8)));

#define TT 4096
#define CCH 512
#define NCH2 64       // chunks per sequence
#define CHL2 64       // timesteps per chunk (TT / NCH2)
#define NSEG 8        // segments for fused pass2
#define SEGC 8        // chunks per segment (NCH2 / NSEG)

// ---------- helpers ----------
__device__ __forceinline__ unsigned short f2bf(float f) {
  unsigned u = __builtin_bit_cast(unsigned, f);
  unsigned r = (u + 0x7FFFu + ((u >> 16) & 1u)) >> 16;
  return (unsigned short)r;
}
__device__ __forceinline__ void gload_lds16(const void* g, void* l) {
  __builtin_amdgcn_global_load_lds(
      (const __attribute__((address_space(1))) unsigned int*)g,
      (__attribute__((address_space(3))) unsigned int*)l, 16, 0, 0);
}
#define VMCNT(n) asm volatile("s_waitcnt vmcnt(" #n ")" ::: "memory")

// ---------- convert x (f32 -> bf16), 4 elems/thread ----------
__global__ __launch_bounds__(256)
void convert_f32_bf16(const float* __restrict__ in, unsigned short* __restrict__ out, int n4) {
  int i = blockIdx.x * 256 + threadIdx.x;
  if (i >= n4) return;
  f4 f = *(const f4*)(in + (size_t)i * 4);
  us4 o = { f2bf(f[0]), f2bf(f[1]), f2bf(f[2]), f2bf(f[3]) };
  *(us4*)(out + (size_t)i * 4) = o;
}

// ---------- transpose+convert weights: in (R x Cc) f32 -> out (Cc x R) bf16 ----------
__global__ __launch_bounds__(256)
void transpose_to_bf16(const float* __restrict__ in, unsigned short* __restrict__ out,
                       int R, int Cc) {
  __shared__ unsigned short tile[32][33];
  int c0 = blockIdx.x * 32, r0 = blockIdx.y * 32;
  int tx = threadIdx.x, ty = threadIdx.y;
  #pragma unroll
  for (int j = 0; j < 32; j += 8)
    tile[ty + j][tx] = f2bf(in[(size_t)(r0 + ty + j) * Cc + c0 + tx]);
  __syncthreads();
  #pragma unroll
  for (int j = 0; j < 32; j += 8)
    out[(size_t)(c0 + ty + j) * R + r0 + tx] = tile[tx][ty + j];
}

// ============ GEMM1: 256x256 tile, BK=64, 8 waves, counted-vmcnt pipeline ============
// (R5 verified structure: 62.5 us, ~0 K-loop bank conflicts)
__global__ __launch_bounds__(512, 2)
void gemm256_g1(const unsigned short* __restrict__ A,
                const unsigned short* __restrict__ BT,
                _Float16* __restrict__ kbuf, _Float16* __restrict__ vbuf,
                _Float16* __restrict__ rbuf) {
  __shared__ char lds[131072];   // A: [0,65536) = 2 slots x 32 KiB; B: [65536,131072)
  const int tid = threadIdx.x;
  const int lane = tid & 63, wv = tid >> 6;
  const int wm = wv >> 2, wn = wv & 3;
  const int ln15 = lane & 15, lq = lane >> 4;

  const int nwg = gridDim.x;
  const int bid = blockIdx.x;
  const int wgid = (nwg % 8 == 0) ? (bid % 8) * (nwg / 8) + bid / 8 : bid;
  const int bn = wgid % 12, bm = wgid / 12;
  const size_t m0 = (size_t)bm * 256, n0 = (size_t)bn * 256;
  const char* Ab = (const char*)(A + m0 * 512);
  const char* Bb = (const char*)(BT + n0 * 512);

  const int srow0 = tid >> 2, srow1 = 128 + (tid >> 2);
  const int sg = tid & 3;
  const int sgs0 = (sg ^ ((srow0 >> 1) & 3)) << 4;
  const int sgs1 = (sg ^ ((srow1 >> 1) & 3)) << 4;

  auto STAGE = [&](int mat, int t, int h) {
    const char* gsrc = mat ? Bb : Ab;
    char* ldst = lds + mat * 65536 + ((t & 1) << 15) + (h << 14);
    const size_t co = (size_t)t * 128 + (size_t)h * 64;
    gload_lds16(gsrc + (size_t)srow0 * 1024 + co + sgs0, ldst + tid * 16);
    gload_lds16(gsrc + (size_t)srow1 * 1024 + co + sgs1, ldst + 8192 + tid * 16);
  };

  f32x4 acc[8][4] = {};
  STAGE(0, 0, 0); STAGE(1, 0, 0); STAGE(0, 0, 1); STAGE(1, 0, 1);

  for (int t = 0; t < 8; ++t) {
    char* Abase = lds + ((t & 1) << 15);
    char* Bbase = lds + 65536 + ((t & 1) << 15);
    // ---- super-phase A (ks = 0) ----
    VMCNT(4);
    __builtin_amdgcn_s_barrier();
    __builtin_amdgcn_sched_barrier(0);
    {
      bf16x8 bf[4], af[8];
      #pragma unroll
      for (int fn = 0; fn < 4; ++fn) {
        const int r = wn * 64 + fn * 16 + ln15;
        bf[fn] = *(const bf16x8*)(Bbase + r * 64 + ((lq ^ ((r >> 1) & 3)) << 4));
      }
      #pragma unroll
      for (int fm = 0; fm < 8; ++fm) {
        const int r = wm * 128 + fm * 16 + ln15;
        af[fm] = *(const bf16x8*)(Abase + r * 64 + ((lq ^ ((r >> 1) & 3)) << 4));
      }
      if (t < 7) { STAGE(0, t + 1, 0); STAGE(1, t + 1, 0); }
      __builtin_amdgcn_s_setprio(1);
      #pragma unroll
      for (int fm = 0; fm < 8; ++fm)
        #pragma unroll
        for (int fn = 0; fn < 4; ++fn)
          acc[fm][fn] = __builtin_amdgcn_mfma_f32_16x16x32_bf16(af[fm], bf[fn], acc[fm][fn], 0, 0, 0);
      __builtin_amdgcn_s_setprio(0);
    }
    // ---- super-phase B (ks = 1) ----
    if (t < 7) { VMCNT(4); } else { VMCNT(0); }
    __builtin_amdgcn_s_barrier();
    __builtin_amdgcn_sched_barrier(0);
    {
      bf16x8 bf[4], af[8];
      #pragma unroll
      for (int fn = 0; fn < 4; ++fn) {
        const int r = wn * 64 + fn * 16 + ln15;
        bf[fn] = *(const bf16x8*)(Bbase + 16384 + r * 64 + ((lq ^ ((r >> 1) & 3)) << 4));
      }
      #pragma unroll
      for (int fm = 0; fm < 8; ++fm) {
        const int r = wm * 128 + fm * 16 + ln15;
        af[fm] = *(const bf16x8*)(Abase + 16384 + r * 64 + ((lq ^ ((r >> 1) & 3)) << 4));
      }
      if (t < 7) { STAGE(0, t + 1, 1); STAGE(1, t + 1, 1); }
      __builtin_amdgcn_s_setprio(1);
      #pragma unroll
      for (int fm = 0; fm < 8; ++fm)
        #pragma unroll
        for (int fn = 0; fn < 4; ++fn)
          acc[fm][fn] = __builtin_amdgcn_mfma_f32_16x16x32_bf16(af[fm], bf[fn], acc[fm][fn], 0, 0, 0);
      __builtin_amdgcn_s_setprio(0);
    }
  }

  // ---- epilogue: LDS-staged coalesced f16 stores ----
  const int n0i = (int)n0;
  const int dir = (n0i >= 1536) ? 1 : 0;
  const int jj0 = n0i - dir * 1536;
  const int seg = jj0 >> 9;
  const int cbase = jj0 & 511;           // 0 or 256
  _Float16* dbuf = (seg == 0) ? rbuf : (seg == 1 ? kbuf : vbuf);
  float* stg = (float*)lds;              // [2][32][256] f32 (64 KiB)
  const int ebnd = wv >> 2;              // == wm
  const int erow = (tid >> 3) & 31;
  const int el8 = tid & 7;
  __syncthreads();
  #pragma unroll
  for (int gi = 0; gi < 4; ++gi) {
    #pragma unroll
    for (int f2 = 0; f2 < 2; ++f2) {
      const int fm = gi * 2 + f2;
      #pragma unroll
      for (int q = 0; q < 4; ++q) {
        const int rloc = f2 * 16 + lq * 4 + q;
        float* dst = stg + wm * 8192 + rloc * 256;
        const int sw = ((rloc >> 2) & 1) << 4;
        #pragma unroll
        for (int fn = 0; fn < 4; ++fn)
          dst[(wn * 64 + fn * 16 + ln15) ^ sw] = acc[fm][fn][q];
      }
    }
    __syncthreads();
    {
      const int rowg = (int)m0 + ebnd * 128 + gi * 32 + erow;
      const int b_ = rowg >> 12, tt = rowg & 4095;
      const int trow = dir ? (4095 - tt) : tt;
      _Float16* gp = dbuf + ((size_t)(b_ * 2 + dir) * TT + trow) * 512 + cbase;
      const float* sp = stg + ebnd * 8192 + erow * 256;
      const int sw = ((erow >> 2) & 1) << 4;
      #pragma unroll
      for (int u = 0; u < 4; ++u) {
        const int cf = el8 * 8 + u * 64;
        const int cs = cf ^ sw;
        f4 a = *(const f4*)(sp + cs);
        f4 b = *(const f4*)(sp + cs + 4);
        h8 hv = { (_Float16)a[0], (_Float16)a[1], (_Float16)a[2], (_Float16)a[3],
                  (_Float16)b[0], (_Float16)b[1], (_Float16)b[2], (_Float16)b[3] };
        *(h8*)(gp + cf) = hv;
      }
    }
    __syncthreads();
  }
}

// ---------- 128x128 bf16 MFMA GEMM — used for GEMM2 ----------
__global__ __launch_bounds__(256)
void gemm_bf16_m1(const unsigned short* __restrict__ A, int lda,
                  const unsigned short* __restrict__ BT, int ldb,
                  int M, int N, int K, float* __restrict__ out) {
  __shared__ char smem[16384];
  unsigned short* As  = (unsigned short*)smem;
  unsigned short* Bsm = (unsigned short*)(smem + 8192);
  const int tid = threadIdx.x;
  const int lane = tid & 63, wv = tid >> 6;
  const int wr = wv >> 1, wc = wv & 1;
  const int ln15 = lane & 15, lq = lane >> 4;
  const int mtiles = M >> 7;
  const int bm = blockIdx.x % mtiles, bn = blockIdx.x / mtiles;
  const size_t m0 = (size_t)bm << 7, n0 = (size_t)bn << 7;
  f32x4 acc[4][4] = {};
  const char* Ab = (const char*)(A + m0 * (size_t)lda);
  const char* Bb = (const char*)(BT + n0 * (size_t)ldb);
  const int r0 = tid >> 2;
  const int cb = (((tid & 3) ^ (r0 & 3)) << 4);
  const size_t ldab = (size_t)lda * 2, ldbb = (size_t)ldb * 2;

  for (int k0 = 0; k0 < K; k0 += 32) {
    const size_t kb = (size_t)k0 * 2;
    gload_lds16(Ab + (size_t)r0 * ldab + kb + cb,        (char*)As + tid * 16);
    gload_lds16(Ab + (size_t)(r0 + 64) * ldab + kb + cb, (char*)As + 4096 + tid * 16);
    gload_lds16(Bb + (size_t)r0 * ldbb + kb + cb,        (char*)Bsm + tid * 16);
    gload_lds16(Bb + (size_t)(r0 + 64) * ldbb + kb + cb, (char*)Bsm + 4096 + tid * 16);
    __syncthreads();
    bf16x8 af[4], bg[4];
    #pragma unroll
    for (int i = 0; i < 4; ++i) {
      const int ar = wr * 64 + i * 16 + ln15;
      const int br = wc * 64 + i * 16 + ln15;
      af[i] = *(const bf16x8*)((char*)As  + ((ar * 4 + (lq ^ (ar & 3))) << 4));
      bg[i] = *(const bf16x8*)((char*)Bsm + ((br * 4 + (lq ^ (br & 3))) << 4));
    }
    #pragma unroll
    for (int i = 0; i < 4; ++i)
      #pragma unroll
      for (int j = 0; j < 4; ++j)
        acc[i][j] = __builtin_amdgcn_mfma_f32_16x16x32_bf16(af[i], bg[j], acc[i][j], 0, 0, 0);
    __syncthreads();
  }

  const int tq = tid >> 3, t8 = tid & 7;
  #pragma unroll
  for (int i = 0; i < 4; ++i) {
    __syncthreads();
    float* st = (float*)smem;
    #pragma unroll
    for (int j = 0; j < 4; ++j) {
      const int cl = wc * 64 + j * 16 + ln15;
      #pragma unroll
      for (int q = 0; q < 4; ++q) {
        const int rl = wr * 16 + lq * 4 + q;
        st[rl * 128 + (cl ^ (((rl >> 2) & 3) << 4))] = acc[i][j][q];
      }
    }
    __syncthreads();
    const int rl = tq, lqp = (rl >> 2) & 3;
    const int lr = ((rl >> 4) << 6) + (i << 4) + (rl & 15);
    const int rowg = (int)m0 + lr;
    #pragma unroll
    for (int u = 0; u < 4; ++u) {
      const int colL = t8 * 16 + u * 4;
      const int colS = colL ^ (lqp << 4);
      f4 vv = *(const f4*)(st + rl * 128 + colS);
      *(f4*)(out + (size_t)rowg * N + n0 + colL) = vv;
    }
  }
}

// ---------- WKV chunked scan (h8-vectorized: 8 channels/thread, 64 thr/chunk) ----------
// pass1: per-chunk local end-state. block (64,2): 2 chunks per block.
__global__ __launch_bounds__(128)
void wkv_pass1(const _Float16* __restrict__ kbuf, const _Float16* __restrict__ vbuf,
               const float* __restrict__ td, const float* __restrict__ tdr,
               float* __restrict__ cN, float* __restrict__ cD, float* __restrict__ cM) {
  const int bd = blockIdx.x;
  const int ch = blockIdx.y * 2 + threadIdx.y;
  const int dir = bd & 1;
  const int c = threadIdx.x * 8;
  const float* tdp = (dir ? tdr : td) + c;
  float w[8], num[8], den[8], m[8];
  #pragma unroll
  for (int e = 0; e < 8; ++e) { w[e] = -__expf(tdp[e]); num[e] = 0.f; den[e] = 0.f; m[e] = -1e38f; }
  const size_t base = ((size_t)bd * TT + (size_t)ch * CHL2) * CCH + c;
  const _Float16* kp = kbuf + base;
  const _Float16* vp = vbuf + base;
  h8 ka = *(const h8*)(kp), va = *(const h8*)(vp);
  h8 kb = *(const h8*)(kp + CCH), vb = *(const h8*)(vp + CCH);
  for (int t = 0; t < CHL2; ++t) {
    h8 kc = {}, vc = {};
    if (t + 2 < CHL2) {
      kc = *(const h8*)(kp + (size_t)(t + 2) * CCH);
      vc = *(const h8*)(vp + (size_t)(t + 2) * CCH);
    }
    #pragma unroll
    for (int e = 0; e < 8; ++e) {
      float ke = (float)ka[e], ve = (float)va[e];
      float mw = m[e] + w[e];
      float m2 = fmaxf(mw, ke);
      float e1 = __expf(mw - m2), e2 = __expf(ke - m2);
      num[e] = e1 * num[e] + e2 * ve;
      den[e] = e1 * den[e] + e2;
      m[e] = m2;
    }
    ka = kb; va = vb; kb = kc; vb = vc;
  }
  const size_t ci = ((size_t)bd * NCH2 + ch) * CCH + c;
  #pragma unroll
  for (int h = 0; h < 2; ++h) {
    *(f4*)(cN + ci + h * 4) = (f4){num[h*4], num[h*4+1], num[h*4+2], num[h*4+3]};
    *(f4*)(cD + ci + h * 4) = (f4){den[h*4], den[h*4+1], den[h*4+2], den[h*4+3]};
    *(f4*)(cM + ci + h * 4) = (f4){m[h*4], m[h*4+1], m[h*4+2], m[h*4+3]};
  }
}

// pass2 (fused a+b+c): hierarchical carry combine, seg carries in LDS.
// Each thread owns ONE channel column -> no barriers needed.
__global__ __launch_bounds__(128)
void wkv_pass2f(const float* __restrict__ td, const float* __restrict__ tdr,
                float* __restrict__ cN, float* __restrict__ cD, float* __restrict__ cM) {
  __shared__ float sN[NSEG][128], sD[NSEG][128], sM[NSEG][128];
  const int bd = blockIdx.x, cg = blockIdx.y;
  const int dir = bd & 1;
  const int tx = threadIdx.x;
  const int c = cg * 128 + tx;
  const float wchl = -__expf((dir ? tdr : td)[c]) * (float)CHL2;   // per-chunk decay
  const float wseg = wchl * (float)SEGC;                           // per-segment decay
  const size_t base = (size_t)bd * NCH2 * CCH + c;
  // phase a: per-segment local combine
  for (int seg = 0; seg < NSEG; ++seg) {
    float n = 0.f, d = 0.f, m = -1e38f;
    size_t ci = base + (size_t)seg * SEGC * CCH;
    for (int j = 0; j < SEGC; ++j, ci += CCH) {
      float ln = cN[ci], ld = cD[ci], lm = cM[ci];
      float mp = m + wchl, mm = fmaxf(mp, lm);
      float e1 = __expf(mp - mm), e2 = __expf(lm - mm);
      n = e1 * n + e2 * ln; d = e1 * d + e2 * ld; m = mm;
    }
    sN[seg][tx] = n; sD[seg][tx] = d; sM[seg][tx] = m;
  }
  // phase b: serial exclusive scan over segment carries (thread-private column)
  {
    float n = 0.f, d = 0.f, m = -1e38f;
    for (int seg = 0; seg < NSEG; ++seg) {
      float tn = sN[seg][tx], tdv = sD[seg][tx], tm = sM[seg][tx];
      sN[seg][tx] = n; sD[seg][tx] = d; sM[seg][tx] = m;
      float mp = m + wseg, mm = fmaxf(mp, tm);
      float e1 = __expf(mp - mm), e2 = __expf(tm - mm);
      n = e1 * n + e2 * tn; d = e1 * d + e2 * tdv; m = mm;
    }
  }
  // phase c: replay segments, rewrite chunk slots with exclusive prefix
  for (int seg = 0; seg < NSEG; ++seg) {
    float n = sN[seg][tx], d = sD[seg][tx], m = sM[seg][tx];
    size_t ci = base + (size_t)seg * SEGC * CCH;
    for (int j = 0; j < SEGC; ++j, ci += CCH) {
      float ln = cN[ci], ld = cD[ci], lm = cM[ci];
      cN[ci] = n; cD[ci] = d; cM[ci] = m;
      float mp = m + wchl, mm = fmaxf(mp, lm);
      float e1 = __expf(mp - mm), e2 = __expf(lm - mm);
      n = e1 * n + e2 * ln; d = e1 * d + e2 * ld; m = mm;
    }
  }
}

// pass3: replay each chunk from its carry, emit sigmoid(r) * y. block (64,2).
__global__ __launch_bounds__(128)
void wkv_pass3(const _Float16* __restrict__ kbuf, const _Float16* __restrict__ vbuf,
               const _Float16* __restrict__ rbuf,
               const float* __restrict__ td, const float* __restrict__ tf,
               const float* __restrict__ tdr, const float* __restrict__ tfr,
               const float* __restrict__ cN, const float* __restrict__ cD,
               const float* __restrict__ cM,
               unsigned short* __restrict__ ocat) {
  const int bd = blockIdx.x;
  const int ch = blockIdx.y * 2 + threadIdx.y;
  const int b = bd >> 1, dir = bd & 1;
  const int c = threadIdx.x * 8;
  const float* tdp = (dir ? tdr : td) + c;
  const float* tup = (dir ? tfr : tf) + c;
  const size_t ci = ((size_t)bd * NCH2 + ch) * CCH + c;
  float w[8], u[8], num[8], den[8], m[8];
  #pragma unroll
  for (int e = 0; e < 8; ++e) {
    w[e] = -__expf(tdp[e]); u[e] = tup[e];
    num[e] = cN[ci + e]; den[e] = cD[ci + e]; m[e] = cM[ci + e];
  }
  const size_t base = ((size_t)bd * TT + (size_t)ch * CHL2) * CCH + c;
  const _Float16* kp = kbuf + base;
  const _Float16* vp = vbuf + base;
  const _Float16* rp = rbuf + base;
  h8 ka = *(const h8*)(kp), va = *(const h8*)(vp), ra = *(const h8*)(rp);
  h8 kb = *(const h8*)(kp + CCH), vb = *(const h8*)(vp + CCH), rb = *(const h8*)(rp + CCH);
  for (int t = 0; t < CHL2; ++t) {
    h8 kc = {}, vc = {}, rc = {};
    if (t + 2 < CHL2) {
      kc = *(const h8*)(kp + (size_t)(t + 2) * CCH);
      vc = *(const h8*)(vp + (size_t)(t + 2) * CCH);
      rc = *(const h8*)(rp + (size_t)(t + 2) * CCH);
    }
    const int tnat = ch * CHL2 + t;
    const int tact = dir ? (TT - 1 - tnat) : tnat;
    unsigned short o[8];
    #pragma unroll
    for (int e = 0; e < 8; ++e) {
      float ke = (float)ka[e], ve = (float)va[e];
      float ku = ke + u[e];
      float mm = fmaxf(m[e], ku);
      float e1 = __expf(m[e] - mm), e2 = __expf(ku - mm);
      float y = (e1 * num[e] + e2 * ve) * __builtin_amdgcn_rcpf(e1 * den[e] + e2);
      float rt = (float)ra[e];
      float sig = __builtin_amdgcn_rcpf(1.f + __expf(-rt));
      o[e] = f2bf(sig * y);
      float mw = m[e] + w[e];
      float m2 = fmaxf(mw, ke);
      float es1 = __expf(mw - m2), es2 = __expf(ke - m2);
      num[e] = es1 * num[e] + es2 * ve;
      den[e] = es1 * den[e] + es2;
      m[e] = m2;
    }
    us8 ov = { o[0], o[1], o[2], o[3], o[4], o[5], o[6], o[7] };
    *(us8*)(ocat + (((size_t)b * TT + tact) * 2 + dir) * CCH + c) = ov;
    ka = kb; va = vb; ra = rb; kb = kc; vb = vc; rb = rc;
  }
}

// ---------- launch ----------
extern "C" void kernel_launch(void* const* d_in, const int* in_sizes, int n_in,
                              void* d_out, int out_size, void* d_ws, size_t ws_size,
                              hipStream_t stream) {
  const float* x   = (const float*)d_in[0];
  const float* Wr  = (const float*)d_in[1];
  const float* Wo  = (const float*)d_in[2];
  const float* td  = (const float*)d_in[3];
  const float* tf  = (const float*)d_in[4];
  const float* tdr = (const float*)d_in[5];
  const float* tfr = (const float*)d_in[6];
  float* out = (float*)d_out;

  auto rnd = [](size_t b) { return (b + 255) & ~(size_t)255; };
  const size_t wBytes = rnd((size_t)3072 * 512 * 2) + rnd((size_t)512 * 1024 * 2);
  auto need = [&](int Bs) {
    size_t s = wBytes;
    s += 3 * rnd((size_t)Bs * 2 * TT * 512 * 2);              // k, v, r (f16)
    s += rnd((size_t)Bs * TT * 1024 * 2);                     // ocat (bf16) >= xb
    s += 3 * rnd((size_t)Bs * 2 * (size_t)NCH2 * 512 * 4);    // chunk carries (f32)
    return s;
  };
  int Bs = 8;
  while (Bs > 1 && need(Bs) > ws_size) Bs >>= 1;

  char* ws = (char*)d_ws;
  size_t off = 0;
  auto alloc = [&](size_t bytes) -> char* {
    char* p = ws + off;
    off += (bytes + 255) & ~(size_t)255;
    return p;
  };
  unsigned short* wrkvT = (unsigned short*)alloc((size_t)3072 * 512 * 2);
  unsigned short* woutT = (unsigned short*)alloc((size_t)512 * 1024 * 2);
  _Float16*       kbuf  = (_Float16*)alloc((size_t)Bs * 2 * TT * 512 * 2);
  _Float16*       vbuf  = (_Float16*)alloc((size_t)Bs * 2 * TT * 512 * 2);
  _Float16*       rbuf  = (_Float16*)alloc((size_t)Bs * 2 * TT * 512 * 2);
  unsigned short* ocat  = (unsigned short*)alloc((size_t)Bs * TT * 1024 * 2);
  unsigned short* xb    = ocat;   // alias: xb consumed by GEMM1 before pass3 writes ocat
  float*          cN    = (float*)alloc((size_t)Bs * 2 * (size_t)NCH2 * 512 * 4);
  float*          cD    = (float*)alloc((size_t)Bs * 2 * (size_t)NCH2 * 512 * 4);
  float*          cM    = (float*)alloc((size_t)Bs * 2 * (size_t)NCH2 * 512 * 4);

  transpose_to_bf16<<<dim3(3072 / 32, 512 / 32), dim3(32, 8), 0, stream>>>(Wr, wrkvT, 512, 3072);
  transpose_to_bf16<<<dim3(512 / 32, 1024 / 32), dim3(32, 8), 0, stream>>>(Wo, woutT, 1024, 512);

  const int nslices = 8 / Bs;
  const int Mslice = Bs * TT;
  const int mt256 = Mslice >> 8;
  const int mt128 = Mslice >> 7;
  for (int s = 0; s < nslices; ++s) {
    const float* xs = x + (size_t)s * Mslice * 512;
    float* outs = out + (size_t)s * Mslice * 512;
    // 1. convert x slice to bf16
    convert_f32_bf16<<<Mslice * 512 / 1024, 256, 0, stream>>>(xs, xb, Mslice * 512 / 4);
    // 2. GEMM1 (256^2 pipelined): rkv = x @ W_rkv -> k/v/r (f16)
    gemm256_g1<<<mt256 * 12, 512, 0, stream>>>(xb, wrkvT, kbuf, vbuf, rbuf);
    // 3. WKV chunked scan: pass1 (local), fused pass2, pass3 (emit)
    wkv_pass1<<<dim3(Bs * 2, NCH2 / 2), dim3(64, 2), 0, stream>>>(kbuf, vbuf, td, tdr, cN, cD, cM);
    wkv_pass2f<<<dim3(Bs * 2, 4), 128, 0, stream>>>(td, tdr, cN, cD, cM);
    wkv_pass3<<<dim3(Bs * 2, NCH2 / 2), dim3(64, 2), 0, stream>>>(kbuf, vbuf, rbuf, td, tf, tdr, tfr,
                                                                  cN, cD, cM, ocat);
    // 4. GEMM2: out = out_cat @ W_out
    gemm_bf16_m1<<<mt128 * 4, 256, 0, stream>>>(ocat, 1024, woutT, 1024, Mslice, 512, 1024, outs);
  }
}

// Round 11
// 373.442 us; speedup vs baseline: 1.1682x; 1.1682x over previous
//
#include <hip/hip_runtime.h>

// ---------- types ----------
typedef float f4 __attribute__((ext_vector_type(4)));
typedef unsigned short us4 __attribute__((ext_vector_type(4)));
typedef unsigned short us8 __attribute__((ext_vector_type(8)));
typedef __bf16 bf16x8 __attribute__((ext_vector_type(8)));
typedef float f32x4 __attribute__((ext_vector_type(4)));
typedef _Float16 h8 __attribute__((ext_vector_type(8)));

#define TT 4096
#define CCH 512
#define NCH2 256      // chunks per sequence
#define CHL2 16       // timesteps per chunk (TT / NCH2)
#define NSEG 32       // segments for hierarchical pass2
#define SEGC 8        // chunks per segment (NCH2 / NSEG)

// ---------- helpers ----------
__device__ __forceinline__ unsigned short f2bf(float f) {
  unsigned u = __builtin_bit_cast(unsigned, f);
  unsigned r = (u + 0x7FFFu + ((u >> 16) & 1u)) >> 16;
  return (unsigned short)r;
}
__device__ __forceinline__ void gload_lds16(const void* g, void* l) {
  __builtin_amdgcn_global_load_lds(
      (const __attribute__((address_space(1))) unsigned int*)g,
      (__attribute__((address_space(3))) unsigned int*)l, 16, 0, 0);
}
#define VMCNT(n) asm volatile("s_waitcnt vmcnt(" #n ")" ::: "memory")

// ---------- convert x (f32 -> bf16), 4 elems/thread ----------
__global__ __launch_bounds__(256)
void convert_f32_bf16(const float* __restrict__ in, unsigned short* __restrict__ out, int n4) {
  int i = blockIdx.x * 256 + threadIdx.x;
  if (i >= n4) return;
  f4 f = *(const f4*)(in + (size_t)i * 4);
  us4 o = { f2bf(f[0]), f2bf(f[1]), f2bf(f[2]), f2bf(f[3]) };
  *(us4*)(out + (size_t)i * 4) = o;
}

// ---------- transpose+convert weights: in (R x Cc) f32 -> out (Cc x R) bf16 ----------
__global__ __launch_bounds__(256)
void transpose_to_bf16(const float* __restrict__ in, unsigned short* __restrict__ out,
                       int R, int Cc) {
  __shared__ unsigned short tile[32][33];
  int c0 = blockIdx.x * 32, r0 = blockIdx.y * 32;
  int tx = threadIdx.x, ty = threadIdx.y;
  #pragma unroll
  for (int j = 0; j < 32; j += 8)
    tile[ty + j][tx] = f2bf(in[(size_t)(r0 + ty + j) * Cc + c0 + tx]);
  __syncthreads();
  #pragma unroll
  for (int j = 0; j < 32; j += 8)
    out[(size_t)(c0 + ty + j) * R + r0 + tx] = tile[tx][ty + j];
}

// ============ GEMM1: 256x256 tile, BK=64, 8 waves, counted-vmcnt pipeline ============
// (R5 verified structure: 62.5 us, ~0 K-loop bank conflicts)
__global__ __launch_bounds__(512, 2)
void gemm256_g1(const unsigned short* __restrict__ A,
                const unsigned short* __restrict__ BT,
                _Float16* __restrict__ kbuf, _Float16* __restrict__ vbuf,
                _Float16* __restrict__ rbuf) {
  __shared__ char lds[131072];   // A: [0,65536) = 2 slots x 32 KiB; B: [65536,131072)
  const int tid = threadIdx.x;
  const int lane = tid & 63, wv = tid >> 6;
  const int wm = wv >> 2, wn = wv & 3;
  const int ln15 = lane & 15, lq = lane >> 4;

  const int nwg = gridDim.x;
  const int bid = blockIdx.x;
  const int wgid = (nwg % 8 == 0) ? (bid % 8) * (nwg / 8) + bid / 8 : bid;
  const int bn = wgid % 12, bm = wgid / 12;
  const size_t m0 = (size_t)bm * 256, n0 = (size_t)bn * 256;
  const char* Ab = (const char*)(A + m0 * 512);
  const char* Bb = (const char*)(BT + n0 * 512);

  const int srow0 = tid >> 2, srow1 = 128 + (tid >> 2);
  const int sg = tid & 3;
  const int sgs0 = (sg ^ ((srow0 >> 1) & 3)) << 4;
  const int sgs1 = (sg ^ ((srow1 >> 1) & 3)) << 4;

  auto STAGE = [&](int mat, int t, int h) {
    const char* gsrc = mat ? Bb : Ab;
    char* ldst = lds + mat * 65536 + ((t & 1) << 15) + (h << 14);
    const size_t co = (size_t)t * 128 + (size_t)h * 64;
    gload_lds16(gsrc + (size_t)srow0 * 1024 + co + sgs0, ldst + tid * 16);
    gload_lds16(gsrc + (size_t)srow1 * 1024 + co + sgs1, ldst + 8192 + tid * 16);
  };

  f32x4 acc[8][4] = {};
  STAGE(0, 0, 0); STAGE(1, 0, 0); STAGE(0, 0, 1); STAGE(1, 0, 1);

  for (int t = 0; t < 8; ++t) {
    char* Abase = lds + ((t & 1) << 15);
    char* Bbase = lds + 65536 + ((t & 1) << 15);
    // ---- super-phase A (ks = 0) ----
    VMCNT(4);
    __builtin_amdgcn_s_barrier();
    __builtin_amdgcn_sched_barrier(0);
    {
      bf16x8 bf[4], af[8];
      #pragma unroll
      for (int fn = 0; fn < 4; ++fn) {
        const int r = wn * 64 + fn * 16 + ln15;
        bf[fn] = *(const bf16x8*)(Bbase + r * 64 + ((lq ^ ((r >> 1) & 3)) << 4));
      }
      #pragma unroll
      for (int fm = 0; fm < 8; ++fm) {
        const int r = wm * 128 + fm * 16 + ln15;
        af[fm] = *(const bf16x8*)(Abase + r * 64 + ((lq ^ ((r >> 1) & 3)) << 4));
      }
      if (t < 7) { STAGE(0, t + 1, 0); STAGE(1, t + 1, 0); }
      __builtin_amdgcn_s_setprio(1);
      #pragma unroll
      for (int fm = 0; fm < 8; ++fm)
        #pragma unroll
        for (int fn = 0; fn < 4; ++fn)
          acc[fm][fn] = __builtin_amdgcn_mfma_f32_16x16x32_bf16(af[fm], bf[fn], acc[fm][fn], 0, 0, 0);
      __builtin_amdgcn_s_setprio(0);
    }
    // ---- super-phase B (ks = 1) ----
    if (t < 7) { VMCNT(4); } else { VMCNT(0); }
    __builtin_amdgcn_s_barrier();
    __builtin_amdgcn_sched_barrier(0);
    {
      bf16x8 bf[4], af[8];
      #pragma unroll
      for (int fn = 0; fn < 4; ++fn) {
        const int r = wn * 64 + fn * 16 + ln15;
        bf[fn] = *(const bf16x8*)(Bbase + 16384 + r * 64 + ((lq ^ ((r >> 1) & 3)) << 4));
      }
      #pragma unroll
      for (int fm = 0; fm < 8; ++fm) {
        const int r = wm * 128 + fm * 16 + ln15;
        af[fm] = *(const bf16x8*)(Abase + 16384 + r * 64 + ((lq ^ ((r >> 1) & 3)) << 4));
      }
      if (t < 7) { STAGE(0, t + 1, 1); STAGE(1, t + 1, 1); }
      __builtin_amdgcn_s_setprio(1);
      #pragma unroll
      for (int fm = 0; fm < 8; ++fm)
        #pragma unroll
        for (int fn = 0; fn < 4; ++fn)
          acc[fm][fn] = __builtin_amdgcn_mfma_f32_16x16x32_bf16(af[fm], bf[fn], acc[fm][fn], 0, 0, 0);
      __builtin_amdgcn_s_setprio(0);
    }
  }

  // ---- epilogue: LDS-staged coalesced f16 stores ----
  const int n0i = (int)n0;
  const int dir = (n0i >= 1536) ? 1 : 0;
  const int jj0 = n0i - dir * 1536;
  const int seg = jj0 >> 9;
  const int cbase = jj0 & 511;           // 0 or 256
  _Float16* dbuf = (seg == 0) ? rbuf : (seg == 1 ? kbuf : vbuf);
  float* stg = (float*)lds;              // [2][32][256] f32 (64 KiB)
  const int ebnd = wv >> 2;              // == wm
  const int erow = (tid >> 3) & 31;
  const int el8 = tid & 7;
  __syncthreads();
  #pragma unroll
  for (int gi = 0; gi < 4; ++gi) {
    #pragma unroll
    for (int f2 = 0; f2 < 2; ++f2) {
      const int fm = gi * 2 + f2;
      #pragma unroll
      for (int q = 0; q < 4; ++q) {
        const int rloc = f2 * 16 + lq * 4 + q;
        float* dst = stg + wm * 8192 + rloc * 256;
        const int sw = ((rloc >> 2) & 1) << 4;
        #pragma unroll
        for (int fn = 0; fn < 4; ++fn)
          dst[(wn * 64 + fn * 16 + ln15) ^ sw] = acc[fm][fn][q];
      }
    }
    __syncthreads();
    {
      const int rowg = (int)m0 + ebnd * 128 + gi * 32 + erow;
      const int b_ = rowg >> 12, tt = rowg & 4095;
      const int trow = dir ? (4095 - tt) : tt;
      _Float16* gp = dbuf + ((size_t)(b_ * 2 + dir) * TT + trow) * 512 + cbase;
      const float* sp = stg + ebnd * 8192 + erow * 256;
      const int sw = ((erow >> 2) & 1) << 4;
      #pragma unroll
      for (int u = 0; u < 4; ++u) {
        const int cf = el8 * 8 + u * 64;
        const int cs = cf ^ sw;
        f4 a = *(const f4*)(sp + cs);
        f4 b = *(const f4*)(sp + cs + 4);
        h8 hv = { (_Float16)a[0], (_Float16)a[1], (_Float16)a[2], (_Float16)a[3],
                  (_Float16)b[0], (_Float16)b[1], (_Float16)b[2], (_Float16)b[3] };
        *(h8*)(gp + cf) = hv;
      }
    }
    __syncthreads();
  }
}

// ---------- 128x128 bf16 MFMA GEMM — used for GEMM2 ----------
__global__ __launch_bounds__(256)
void gemm_bf16_m1(const unsigned short* __restrict__ A, int lda,
                  const unsigned short* __restrict__ BT, int ldb,
                  int M, int N, int K, float* __restrict__ out) {
  __shared__ char smem[16384];
  unsigned short* As  = (unsigned short*)smem;
  unsigned short* Bsm = (unsigned short*)(smem + 8192);
  const int tid = threadIdx.x;
  const int lane = tid & 63, wv = tid >> 6;
  const int wr = wv >> 1, wc = wv & 1;
  const int ln15 = lane & 15, lq = lane >> 4;
  const int mtiles = M >> 7;
  const int bm = blockIdx.x % mtiles, bn = blockIdx.x / mtiles;
  const size_t m0 = (size_t)bm << 7, n0 = (size_t)bn << 7;
  f32x4 acc[4][4] = {};
  const char* Ab = (const char*)(A + m0 * (size_t)lda);
  const char* Bb = (const char*)(BT + n0 * (size_t)ldb);
  const int r0 = tid >> 2;
  const int cb = (((tid & 3) ^ (r0 & 3)) << 4);
  const size_t ldab = (size_t)lda * 2, ldbb = (size_t)ldb * 2;

  for (int k0 = 0; k0 < K; k0 += 32) {
    const size_t kb = (size_t)k0 * 2;
    gload_lds16(Ab + (size_t)r0 * ldab + kb + cb,        (char*)As + tid * 16);
    gload_lds16(Ab + (size_t)(r0 + 64) * ldab + kb + cb, (char*)As + 4096 + tid * 16);
    gload_lds16(Bb + (size_t)r0 * ldbb + kb + cb,        (char*)Bsm + tid * 16);
    gload_lds16(Bb + (size_t)(r0 + 64) * ldbb + kb + cb, (char*)Bsm + 4096 + tid * 16);
    __syncthreads();
    bf16x8 af[4], bg[4];
    #pragma unroll
    for (int i = 0; i < 4; ++i) {
      const int ar = wr * 64 + i * 16 + ln15;
      const int br = wc * 64 + i * 16 + ln15;
      af[i] = *(const bf16x8*)((char*)As  + ((ar * 4 + (lq ^ (ar & 3))) << 4));
      bg[i] = *(const bf16x8*)((char*)Bsm + ((br * 4 + (lq ^ (br & 3))) << 4));
    }
    #pragma unroll
    for (int i = 0; i < 4; ++i)
      #pragma unroll
      for (int j = 0; j < 4; ++j)
        acc[i][j] = __builtin_amdgcn_mfma_f32_16x16x32_bf16(af[i], bg[j], acc[i][j], 0, 0, 0);
    __syncthreads();
  }

  const int tq = tid >> 3, t8 = tid & 7;
  #pragma unroll
  for (int i = 0; i < 4; ++i) {
    __syncthreads();
    float* st = (float*)smem;
    #pragma unroll
    for (int j = 0; j < 4; ++j) {
      const int cl = wc * 64 + j * 16 + ln15;
      #pragma unroll
      for (int q = 0; q < 4; ++q) {
        const int rl = wr * 16 + lq * 4 + q;
        st[rl * 128 + (cl ^ (((rl >> 2) & 3) << 4))] = acc[i][j][q];
      }
    }
    __syncthreads();
    const int rl = tq, lqp = (rl >> 2) & 3;
    const int lr = ((rl >> 4) << 6) + (i << 4) + (rl & 15);
    const int rowg = (int)m0 + lr;
    #pragma unroll
    for (int u = 0; u < 4; ++u) {
      const int colL = t8 * 16 + u * 4;
      const int colS = colL ^ (lqp << 4);
      f4 vv = *(const f4*)(st + rl * 128 + colS);
      *(f4*)(out + (size_t)rowg * N + n0 + colL) = vv;
    }
  }
}

// ---------- WKV chunked scan (NCH2=256 parallelism, h8 16B loads) ----------
// pass1: per-chunk local end-state. block (64,2): 2 chunks/block, 8 ch/thread.
__global__ __launch_bounds__(128)
void wkv_pass1(const _Float16* __restrict__ kbuf, const _Float16* __restrict__ vbuf,
               const float* __restrict__ td, const float* __restrict__ tdr,
               float* __restrict__ cN, float* __restrict__ cD, float* __restrict__ cM) {
  const int bd = blockIdx.x;
  const int ch = blockIdx.y * 2 + threadIdx.y;
  const int dir = bd & 1;
  const int c = threadIdx.x * 8;
  const float* tdp = (dir ? tdr : td) + c;
  float w[8], num[8], den[8], m[8];
  #pragma unroll
  for (int e = 0; e < 8; ++e) { w[e] = -__expf(tdp[e]); num[e] = 0.f; den[e] = 0.f; m[e] = -1e38f; }
  const size_t base = ((size_t)bd * TT + (size_t)ch * CHL2) * CCH + c;
  const _Float16* kp = kbuf + base;
  const _Float16* vp = vbuf + base;
  h8 ka = *(const h8*)(kp), va = *(const h8*)(vp);
  h8 kb = *(const h8*)(kp + CCH), vb = *(const h8*)(vp + CCH);
  for (int t = 0; t < CHL2; ++t) {
    h8 kc = {}, vc = {};
    if (t + 2 < CHL2) {
      kc = *(const h8*)(kp + (size_t)(t + 2) * CCH);
      vc = *(const h8*)(vp + (size_t)(t + 2) * CCH);
    }
    #pragma unroll
    for (int e = 0; e < 8; ++e) {
      float ke = (float)ka[e], ve = (float)va[e];
      float mw = m[e] + w[e];
      float m2 = fmaxf(mw, ke);
      float e1 = __expf(mw - m2), e2 = __expf(ke - m2);
      num[e] = e1 * num[e] + e2 * ve;
      den[e] = e1 * den[e] + e2;
      m[e] = m2;
    }
    ka = kb; va = vb; kb = kc; vb = vc;
  }
  const size_t ci = ((size_t)bd * NCH2 + ch) * CCH + c;
  #pragma unroll
  for (int h = 0; h < 2; ++h) {
    *(f4*)(cN + ci + h * 4) = (f4){num[h*4], num[h*4+1], num[h*4+2], num[h*4+3]};
    *(f4*)(cD + ci + h * 4) = (f4){den[h*4], den[h*4+1], den[h*4+2], den[h*4+3]};
    *(f4*)(cM + ci + h * 4) = (f4){m[h*4], m[h*4+1], m[h*4+2], m[h*4+3]};
  }
}

// pass2a: per-segment combine of SEGC chunk states -> segment carry
__global__ __launch_bounds__(128)
void wkv_p2a(const float* __restrict__ td, const float* __restrict__ tdr,
             const float* __restrict__ cN, const float* __restrict__ cD,
             const float* __restrict__ cM,
             float* __restrict__ scN, float* __restrict__ scD, float* __restrict__ scM) {
  const int bd = blockIdx.x, seg = blockIdx.y;
  const int dir = bd & 1;
  const int c = threadIdx.x * 4;
  f4 tdv = *(const f4*)((dir ? tdr : td) + c);
  float dw[4], num[4], den[4], m[4];
  #pragma unroll
  for (int e = 0; e < 4; ++e) { dw[e] = -__expf(tdv[e]) * (float)CHL2; num[e] = 0.f; den[e] = 0.f; m[e] = -1e38f; }
  size_t ci = ((size_t)bd * NCH2 + (size_t)seg * SEGC) * CCH + c;
  for (int j = 0; j < SEGC; ++j, ci += CCH) {
    f4 ln = *(const f4*)(cN + ci);
    f4 ld = *(const f4*)(cD + ci);
    f4 lm = *(const f4*)(cM + ci);
    #pragma unroll
    for (int e = 0; e < 4; ++e) {
      float mp = m[e] + dw[e];
      float mm = fmaxf(mp, lm[e]);
      float e1 = __expf(mp - mm), e2 = __expf(lm[e] - mm);
      num[e] = e1 * num[e] + e2 * ln[e];
      den[e] = e1 * den[e] + e2 * ld[e];
      m[e] = mm;
    }
  }
  const size_t si = ((size_t)bd * NSEG + seg) * CCH + c;
  *(f4*)(scN + si) = (f4){num[0], num[1], num[2], num[3]};
  *(f4*)(scD + si) = (f4){den[0], den[1], den[2], den[3]};
  *(f4*)(scM + si) = (f4){m[0], m[1], m[2], m[3]};
}

// pass2b: serial exclusive scan over NSEG segment carries (rewrites in place)
__global__ __launch_bounds__(128)
void wkv_p2b(const float* __restrict__ td, const float* __restrict__ tdr,
             float* __restrict__ scN, float* __restrict__ scD, float* __restrict__ scM) {
  const int bd = blockIdx.x;
  const int dir = bd & 1;
  const int c = threadIdx.x * 4;
  f4 tdv = *(const f4*)((dir ? tdr : td) + c);
  float dws[4], num[4], den[4], m[4];
  #pragma unroll
  for (int e = 0; e < 4; ++e) { dws[e] = -__expf(tdv[e]) * (float)(CHL2 * SEGC); num[e] = 0.f; den[e] = 0.f; m[e] = -1e38f; }
  size_t si = (size_t)bd * NSEG * CCH + c;
  for (int s = 0; s < NSEG; ++s, si += CCH) {
    f4 ln = *(const f4*)(scN + si);
    f4 ld = *(const f4*)(scD + si);
    f4 lm = *(const f4*)(scM + si);
    *(f4*)(scN + si) = (f4){num[0], num[1], num[2], num[3]};
    *(f4*)(scD + si) = (f4){den[0], den[1], den[2], den[3]};
    *(f4*)(scM + si) = (f4){m[0], m[1], m[2], m[3]};
    #pragma unroll
    for (int e = 0; e < 4; ++e) {
      float mp = m[e] + dws[e];
      float mm = fmaxf(mp, lm[e]);
      float e1 = __expf(mp - mm), e2 = __expf(lm[e] - mm);
      num[e] = e1 * num[e] + e2 * ln[e];
      den[e] = e1 * den[e] + e2 * ld[e];
      m[e] = mm;
    }
  }
}

// pass2c: replay each segment from its exclusive prefix, rewriting chunk slots
// with the exclusive per-chunk prefix state.
__global__ __launch_bounds__(128)
void wkv_p2c(const float* __restrict__ td, const float* __restrict__ tdr,
             const float* __restrict__ scN, const float* __restrict__ scD,
             const float* __restrict__ scM,
             float* __restrict__ cN, float* __restrict__ cD, float* __restrict__ cM) {
  const int bd = blockIdx.x, seg = blockIdx.y;
  const int dir = bd & 1;
  const int c = threadIdx.x * 4;
  f4 tdv = *(const f4*)((dir ? tdr : td) + c);
  const size_t si = ((size_t)bd * NSEG + seg) * CCH + c;
  f4 nv = *(const f4*)(scN + si);
  f4 dv = *(const f4*)(scD + si);
  f4 mv = *(const f4*)(scM + si);
  float dw[4], num[4], den[4], m[4];
  #pragma unroll
  for (int e = 0; e < 4; ++e) {
    dw[e] = -__expf(tdv[e]) * (float)CHL2;
    num[e] = nv[e]; den[e] = dv[e]; m[e] = mv[e];
  }
  size_t ci = ((size_t)bd * NCH2 + (size_t)seg * SEGC) * CCH + c;
  for (int j = 0; j < SEGC; ++j, ci += CCH) {
    f4 ln = *(const f4*)(cN + ci);
    f4 ld = *(const f4*)(cD + ci);
    f4 lm = *(const f4*)(cM + ci);
    *(f4*)(cN + ci) = (f4){num[0], num[1], num[2], num[3]};
    *(f4*)(cD + ci) = (f4){den[0], den[1], den[2], den[3]};
    *(f4*)(cM + ci) = (f4){m[0], m[1], m[2], m[3]};
    #pragma unroll
    for (int e = 0; e < 4; ++e) {
      float mp = m[e] + dw[e];
      float mm = fmaxf(mp, lm[e]);
      float e1 = __expf(mp - mm), e2 = __expf(lm[e] - mm);
      num[e] = e1 * num[e] + e2 * ln[e];
      den[e] = e1 * den[e] + e2 * ld[e];
      m[e] = mm;
    }
  }
}

// pass3: replay each chunk from its carry, emit sigmoid(r) * y. block (64,2).
__global__ __launch_bounds__(128)
void wkv_pass3(const _Float16* __restrict__ kbuf, const _Float16* __restrict__ vbuf,
               const _Float16* __restrict__ rbuf,
               const float* __restrict__ td, const float* __restrict__ tf,
               const float* __restrict__ tdr, const float* __restrict__ tfr,
               const float* __restrict__ cN, const float* __restrict__ cD,
               const float* __restrict__ cM,
               unsigned short* __restrict__ ocat) {
  const int bd = blockIdx.x;
  const int ch = blockIdx.y * 2 + threadIdx.y;
  const int b = bd >> 1, dir = bd & 1;
  const int c = threadIdx.x * 8;
  const float* tdp = (dir ? tdr : td) + c;
  const float* tup = (dir ? tfr : tf) + c;
  const size_t ci = ((size_t)bd * NCH2 + ch) * CCH + c;
  float w[8], u[8], num[8], den[8], m[8];
  #pragma unroll
  for (int e = 0; e < 8; ++e) {
    w[e] = -__expf(tdp[e]); u[e] = tup[e];
    num[e] = cN[ci + e]; den[e] = cD[ci + e]; m[e] = cM[ci + e];
  }
  const size_t base = ((size_t)bd * TT + (size_t)ch * CHL2) * CCH + c;
  const _Float16* kp = kbuf + base;
  const _Float16* vp = vbuf + base;
  const _Float16* rp = rbuf + base;
  h8 ka = *(const h8*)(kp), va = *(const h8*)(vp), ra = *(const h8*)(rp);
  h8 kb = *(const h8*)(kp + CCH), vb = *(const h8*)(vp + CCH), rb = *(const h8*)(rp + CCH);
  for (int t = 0; t < CHL2; ++t) {
    h8 kc = {}, vc = {}, rc = {};
    if (t + 2 < CHL2) {
      kc = *(const h8*)(kp + (size_t)(t + 2) * CCH);
      vc = *(const h8*)(vp + (size_t)(t + 2) * CCH);
      rc = *(const h8*)(rp + (size_t)(t + 2) * CCH);
    }
    const int tnat = ch * CHL2 + t;
    const int tact = dir ? (TT - 1 - tnat) : tnat;
    unsigned short o[8];
    #pragma unroll
    for (int e = 0; e < 8; ++e) {
      float ke = (float)ka[e], ve = (float)va[e];
      float ku = ke + u[e];
      float mm = fmaxf(m[e], ku);
      float e1 = __expf(m[e] - mm), e2 = __expf(ku - mm);
      float y = (e1 * num[e] + e2 * ve) * __builtin_amdgcn_rcpf(e1 * den[e] + e2);
      float rt = (float)ra[e];
      float sig = __builtin_amdgcn_rcpf(1.f + __expf(-rt));
      o[e] = f2bf(sig * y);
      float mw = m[e] + w[e];
      float m2 = fmaxf(mw, ke);
      float es1 = __expf(mw - m2), es2 = __expf(ke - m2);
      num[e] = es1 * num[e] + es2 * ve;
      den[e] = es1 * den[e] + es2;
      m[e] = m2;
    }
    us8 ov = { o[0], o[1], o[2], o[3], o[4], o[5], o[6], o[7] };
    *(us8*)(ocat + (((size_t)b * TT + tact) * 2 + dir) * CCH + c) = ov;
    ka = kb; va = vb; ra = rb; kb = kc; vb = vc; rb = rc;
  }
}

// ---------- launch ----------
extern "C" void kernel_launch(void* const* d_in, const int* in_sizes, int n_in,
                              void* d_out, int out_size, void* d_ws, size_t ws_size,
                              hipStream_t stream) {
  const float* x   = (const float*)d_in[0];
  const float* Wr  = (const float*)d_in[1];
  const float* Wo  = (const float*)d_in[2];
  const float* td  = (const float*)d_in[3];
  const float* tf  = (const float*)d_in[4];
  const float* tdr = (const float*)d_in[5];
  const float* tfr = (const float*)d_in[6];
  float* out = (float*)d_out;

  auto rnd = [](size_t b) { return (b + 255) & ~(size_t)255; };
  const size_t wBytes = rnd((size_t)3072 * 512 * 2) + rnd((size_t)512 * 1024 * 2);
  auto need = [&](int Bs) {
    size_t s = wBytes;
    s += 3 * rnd((size_t)Bs * 2 * TT * 512 * 2);              // k, v, r (f16)
    s += rnd((size_t)Bs * TT * 1024 * 2);                     // ocat (bf16) >= xb
    s += 3 * rnd((size_t)Bs * 2 * (size_t)NCH2 * 512 * 4);    // chunk carries (f32)
    s += 3 * rnd((size_t)Bs * 2 * (size_t)NSEG * 512 * 4);    // segment carries (f32)
    return s;
  };
  int Bs = 8;
  while (Bs > 1 && need(Bs) > ws_size) Bs >>= 1;

  char* ws = (char*)d_ws;
  size_t off = 0;
  auto alloc = [&](size_t bytes) -> char* {
    char* p = ws + off;
    off += (bytes + 255) & ~(size_t)255;
    return p;
  };
  unsigned short* wrkvT = (unsigned short*)alloc((size_t)3072 * 512 * 2);
  unsigned short* woutT = (unsigned short*)alloc((size_t)512 * 1024 * 2);
  _Float16*       kbuf  = (_Float16*)alloc((size_t)Bs * 2 * TT * 512 * 2);
  _Float16*       vbuf  = (_Float16*)alloc((size_t)Bs * 2 * TT * 512 * 2);
  _Float16*       rbuf  = (_Float16*)alloc((size_t)Bs * 2 * TT * 512 * 2);
  unsigned short* ocat  = (unsigned short*)alloc((size_t)Bs * TT * 1024 * 2);
  unsigned short* xb    = ocat;   // alias: xb consumed by GEMM1 before pass3 writes ocat
  float*          cN    = (float*)alloc((size_t)Bs * 2 * (size_t)NCH2 * 512 * 4);
  float*          cD    = (float*)alloc((size_t)Bs * 2 * (size_t)NCH2 * 512 * 4);
  float*          cM    = (float*)alloc((size_t)Bs * 2 * (size_t)NCH2 * 512 * 4);
  float*          scN   = (float*)alloc((size_t)Bs * 2 * (size_t)NSEG * 512 * 4);
  float*          scD   = (float*)alloc((size_t)Bs * 2 * (size_t)NSEG * 512 * 4);
  float*          scM   = (float*)alloc((size_t)Bs * 2 * (size_t)NSEG * 512 * 4);

  transpose_to_bf16<<<dim3(3072 / 32, 512 / 32), dim3(32, 8), 0, stream>>>(Wr, wrkvT, 512, 3072);
  transpose_to_bf16<<<dim3(512 / 32, 1024 / 32), dim3(32, 8), 0, stream>>>(Wo, woutT, 1024, 512);

  const int nslices = 8 / Bs;
  const int Mslice = Bs * TT;
  const int mt256 = Mslice >> 8;
  const int mt128 = Mslice >> 7;
  for (int s = 0; s < nslices; ++s) {
    const float* xs = x + (size_t)s * Mslice * 512;
    float* outs = out + (size_t)s * Mslice * 512;
    // 1. convert x slice to bf16
    convert_f32_bf16<<<Mslice * 512 / 1024, 256, 0, stream>>>(xs, xb, Mslice * 512 / 4);
    // 2. GEMM1 (256^2 pipelined): rkv = x @ W_rkv -> k/v/r (f16)
    gemm256_g1<<<mt256 * 12, 512, 0, stream>>>(xb, wrkvT, kbuf, vbuf, rbuf);
    // 3. WKV chunked scan: pass1 (local, h8), pass2 a/b/c, pass3 (emit, h8)
    wkv_pass1<<<dim3(Bs * 2, NCH2 / 2), dim3(64, 2), 0, stream>>>(kbuf, vbuf, td, tdr, cN, cD, cM);
    wkv_p2a<<<dim3(Bs * 2, NSEG), 128, 0, stream>>>(td, tdr, cN, cD, cM, scN, scD, scM);
    wkv_p2b<<<Bs * 2, 128, 0, stream>>>(td, tdr, scN, scD, scM);
    wkv_p2c<<<dim3(Bs * 2, NSEG), 128, 0, stream>>>(td, tdr, scN, scD, scM, cN, cD, cM);
    wkv_pass3<<<dim3(Bs * 2, NCH2 / 2), dim3(64, 2), 0, stream>>>(kbuf, vbuf, rbuf, td, tf, tdr, tfr,
                                                                  cN, cD, cM, ocat);
    // 4. GEMM2: out = out_cat @ W_out
    gemm_bf16_m1<<<mt128 * 4, 256, 0, stream>>>(ocat, 1024, woutT, 1024, Mslice, 512, 1024, outs);
  }
}

// Round 12
// 334.310 us; speedup vs baseline: 1.3050x; 1.1171x over previous
//
#include <hip/hip_runtime.h>

// ---------- types ----------
typedef float f4 __attribute__((ext_vector_type(4)));
typedef unsigned short us4 __attribute__((ext_vector_type(4)));
typedef __bf16 bf16x8 __attribute__((ext_vector_type(8)));
typedef float f32x4 __attribute__((ext_vector_type(4)));
typedef _Float16 h8 __attribute__((ext_vector_type(8)));

#define TT 4096
#define CCH 512
#define NCH2 256      // chunks per sequence
#define CHL2 16       // timesteps per chunk (TT / NCH2)
#define NSEG 32       // segments for hierarchical pass2
#define SEGC 8        // chunks per segment (NCH2 / NSEG)

// ---------- helpers ----------
__device__ __forceinline__ unsigned short f2bf(float f) {
  unsigned u = __builtin_bit_cast(unsigned, f);
  unsigned r = (u + 0x7FFFu + ((u >> 16) & 1u)) >> 16;
  return (unsigned short)r;
}
__device__ __forceinline__ void gload_lds16(const void* g, void* l) {
  __builtin_amdgcn_global_load_lds(
      (const __attribute__((address_space(1))) unsigned int*)g,
      (__attribute__((address_space(3))) unsigned int*)l, 16, 0, 0);
}
#define VMCNT(n) asm volatile("s_waitcnt vmcnt(" #n ")" ::: "memory")

// ---------- convert x (f32 -> bf16), 4 elems/thread ----------
__global__ __launch_bounds__(256)
void convert_f32_bf16(const float* __restrict__ in, unsigned short* __restrict__ out, int n4) {
  int i = blockIdx.x * 256 + threadIdx.x;
  if (i >= n4) return;
  f4 f = *(const f4*)(in + (size_t)i * 4);
  us4 o = { f2bf(f[0]), f2bf(f[1]), f2bf(f[2]), f2bf(f[3]) };
  *(us4*)(out + (size_t)i * 4) = o;
}

// ---------- transpose+convert weights: in (R x Cc) f32 -> (Cc x R) bf16 ----------
__global__ __launch_bounds__(256)
void transpose_to_bf16(const float* __restrict__ in, unsigned short* __restrict__ out,
                       int R, int Cc) {
  __shared__ unsigned short tile[32][33];
  int c0 = blockIdx.x * 32, r0 = blockIdx.y * 32;
  int tx = threadIdx.x, ty = threadIdx.y;
  #pragma unroll
  for (int j = 0; j < 32; j += 8)
    tile[ty + j][tx] = f2bf(in[(size_t)(r0 + ty + j) * Cc + c0 + tx]);
  __syncthreads();
  #pragma unroll
  for (int j = 0; j < 32; j += 8)
    out[(size_t)(c0 + ty + j) * R + r0 + tx] = tile[tx][ty + j];
}

// ---------- transpose+convert weights: in (R x Cc) f32 -> (Cc x R) f16 ----------
__global__ __launch_bounds__(256)
void transpose_to_f16(const float* __restrict__ in, _Float16* __restrict__ out,
                      int R, int Cc) {
  __shared__ _Float16 tile[32][33];
  int c0 = blockIdx.x * 32, r0 = blockIdx.y * 32;
  int tx = threadIdx.x, ty = threadIdx.y;
  #pragma unroll
  for (int j = 0; j < 32; j += 8)
    tile[ty + j][tx] = (_Float16)in[(size_t)(r0 + ty + j) * Cc + c0 + tx];
  __syncthreads();
  #pragma unroll
  for (int j = 0; j < 32; j += 8)
    out[(size_t)(c0 + ty + j) * R + r0 + tx] = tile[tx][ty + j];
}

// ============ GEMM1: 256x256 tile, BK=64, 8 waves, counted-vmcnt pipeline ============
// (R5 verified structure: ~62.5 us per 16k-row dispatch, ~0 K-loop bank conflicts)
__global__ __launch_bounds__(512, 2)
void gemm256_g1(const unsigned short* __restrict__ A,
                const unsigned short* __restrict__ BT,
                _Float16* __restrict__ kbuf, _Float16* __restrict__ vbuf,
                _Float16* __restrict__ rbuf) {
  __shared__ char lds[131072];   // A: [0,65536) = 2 slots x 32 KiB; B: [65536,131072)
  const int tid = threadIdx.x;
  const int lane = tid & 63, wv = tid >> 6;
  const int wm = wv >> 2, wn = wv & 3;
  const int ln15 = lane & 15, lq = lane >> 4;

  const int nwg = gridDim.x;
  const int bid = blockIdx.x;
  const int wgid = (nwg % 8 == 0) ? (bid % 8) * (nwg / 8) + bid / 8 : bid;
  const int bn = wgid % 12, bm = wgid / 12;
  const size_t m0 = (size_t)bm * 256, n0 = (size_t)bn * 256;
  const char* Ab = (const char*)(A + m0 * 512);
  const char* Bb = (const char*)(BT + n0 * 512);

  const int srow0 = tid >> 2, srow1 = 128 + (tid >> 2);
  const int sg = tid & 3;
  const int sgs0 = (sg ^ ((srow0 >> 1) & 3)) << 4;
  const int sgs1 = (sg ^ ((srow1 >> 1) & 3)) << 4;

  auto STAGE = [&](int mat, int t, int h) {
    const char* gsrc = mat ? Bb : Ab;
    char* ldst = lds + mat * 65536 + ((t & 1) << 15) + (h << 14);
    const size_t co = (size_t)t * 128 + (size_t)h * 64;
    gload_lds16(gsrc + (size_t)srow0 * 1024 + co + sgs0, ldst + tid * 16);
    gload_lds16(gsrc + (size_t)srow1 * 1024 + co + sgs1, ldst + 8192 + tid * 16);
  };

  f32x4 acc[8][4] = {};
  STAGE(0, 0, 0); STAGE(1, 0, 0); STAGE(0, 0, 1); STAGE(1, 0, 1);

  for (int t = 0; t < 8; ++t) {
    char* Abase = lds + ((t & 1) << 15);
    char* Bbase = lds + 65536 + ((t & 1) << 15);
    // ---- super-phase A (ks = 0) ----
    VMCNT(4);
    __builtin_amdgcn_s_barrier();
    __builtin_amdgcn_sched_barrier(0);
    {
      bf16x8 bf[4], af[8];
      #pragma unroll
      for (int fn = 0; fn < 4; ++fn) {
        const int r = wn * 64 + fn * 16 + ln15;
        bf[fn] = *(const bf16x8*)(Bbase + r * 64 + ((lq ^ ((r >> 1) & 3)) << 4));
      }
      #pragma unroll
      for (int fm = 0; fm < 8; ++fm) {
        const int r = wm * 128 + fm * 16 + ln15;
        af[fm] = *(const bf16x8*)(Abase + r * 64 + ((lq ^ ((r >> 1) & 3)) << 4));
      }
      if (t < 7) { STAGE(0, t + 1, 0); STAGE(1, t + 1, 0); }
      __builtin_amdgcn_s_setprio(1);
      #pragma unroll
      for (int fm = 0; fm < 8; ++fm)
        #pragma unroll
        for (int fn = 0; fn < 4; ++fn)
          acc[fm][fn] = __builtin_amdgcn_mfma_f32_16x16x32_bf16(af[fm], bf[fn], acc[fm][fn], 0, 0, 0);
      __builtin_amdgcn_s_setprio(0);
    }
    // ---- super-phase B (ks = 1) ----
    if (t < 7) { VMCNT(4); } else { VMCNT(0); }
    __builtin_amdgcn_s_barrier();
    __builtin_amdgcn_sched_barrier(0);
    {
      bf16x8 bf[4], af[8];
      #pragma unroll
      for (int fn = 0; fn < 4; ++fn) {
        const int r = wn * 64 + fn * 16 + ln15;
        bf[fn] = *(const bf16x8*)(Bbase + 16384 + r * 64 + ((lq ^ ((r >> 1) & 3)) << 4));
      }
      #pragma unroll
      for (int fm = 0; fm < 8; ++fm) {
        const int r = wm * 128 + fm * 16 + ln15;
        af[fm] = *(const bf16x8*)(Abase + 16384 + r * 64 + ((lq ^ ((r >> 1) & 3)) << 4));
      }
      if (t < 7) { STAGE(0, t + 1, 1); STAGE(1, t + 1, 1); }
      __builtin_amdgcn_s_setprio(1);
      #pragma unroll
      for (int fm = 0; fm < 8; ++fm)
        #pragma unroll
        for (int fn = 0; fn < 4; ++fn)
          acc[fm][fn] = __builtin_amdgcn_mfma_f32_16x16x32_bf16(af[fm], bf[fn], acc[fm][fn], 0, 0, 0);
      __builtin_amdgcn_s_setprio(0);
    }
  }

  // ---- epilogue: LDS-staged coalesced f16 stores ----
  const int n0i = (int)n0;
  const int dir = (n0i >= 1536) ? 1 : 0;
  const int jj0 = n0i - dir * 1536;
  const int seg = jj0 >> 9;
  const int cbase = jj0 & 511;           // 0 or 256
  _Float16* dbuf = (seg == 0) ? rbuf : (seg == 1 ? kbuf : vbuf);
  float* stg = (float*)lds;              // [2][32][256] f32 (64 KiB)
  const int ebnd = wv >> 2;              // == wm
  const int erow = (tid >> 3) & 31;
  const int el8 = tid & 7;
  __syncthreads();
  #pragma unroll
  for (int gi = 0; gi < 4; ++gi) {
    #pragma unroll
    for (int f2 = 0; f2 < 2; ++f2) {
      const int fm = gi * 2 + f2;
      #pragma unroll
      for (int q = 0; q < 4; ++q) {
        const int rloc = f2 * 16 + lq * 4 + q;
        float* dst = stg + wm * 8192 + rloc * 256;
        const int sw = ((rloc >> 2) & 1) << 4;
        #pragma unroll
        for (int fn = 0; fn < 4; ++fn)
          dst[(wn * 64 + fn * 16 + ln15) ^ sw] = acc[fm][fn][q];
      }
    }
    __syncthreads();
    {
      const int rowg = (int)m0 + ebnd * 128 + gi * 32 + erow;
      const int b_ = rowg >> 12, tt = rowg & 4095;
      const int trow = dir ? (4095 - tt) : tt;
      _Float16* gp = dbuf + ((size_t)(b_ * 2 + dir) * TT + trow) * 512 + cbase;
      const float* sp = stg + ebnd * 8192 + erow * 256;
      const int sw = ((erow >> 2) & 1) << 4;
      #pragma unroll
      for (int u = 0; u < 4; ++u) {
        const int cf = el8 * 8 + u * 64;
        const int cs = cf ^ sw;
        f4 a = *(const f4*)(sp + cs);
        f4 b = *(const f4*)(sp + cs + 4);
        h8 hv = { (_Float16)a[0], (_Float16)a[1], (_Float16)a[2], (_Float16)a[3],
                  (_Float16)b[0], (_Float16)b[1], (_Float16)b[2], (_Float16)b[3] };
        *(h8*)(gp + cf) = hv;
      }
    }
    __syncthreads();
  }
}

// ---------- GEMM2: 128x128 f16 MFMA GEMM over the two o-halves ----------
// A row (b*4096+t): cols 0-511 = obufF[b][t][:] (fwd half, natural order),
//                   cols 512-1023 = obufB[b][4095-t][:] (bwd half, scan order).
// obuf = rbuf (pass3 overwrote r with o in place). B = woutT (512 x 1024 f16).
__global__ __launch_bounds__(256)
void gemm2_k(const _Float16* __restrict__ obuf,
             const _Float16* __restrict__ BT,
             int M, float* __restrict__ out) {
  __shared__ char smem[16384];
  _Float16* As  = (_Float16*)smem;
  _Float16* Bsm = (_Float16*)(smem + 8192);
  const int tid = threadIdx.x;
  const int lane = tid & 63, wv = tid >> 6;
  const int wr = wv >> 1, wc = wv & 1;
  const int ln15 = lane & 15, lq = lane >> 4;
  const int mtiles = M >> 7;
  const int bm = blockIdx.x % mtiles, bn = blockIdx.x / mtiles;
  const size_t m0 = (size_t)bm << 7, n0 = (size_t)bn << 7;
  f32x4 acc[4][4] = {};
  const int bB = (int)(m0 >> 12);          // batch of this tile (4096-aligned tiles)
  const int tbase = (int)(m0 & 4095);
  const char* Bb = (const char*)(BT + n0 * 1024);
  const int r0 = tid >> 2;
  const int cb = (((tid & 3) ^ (r0 & 3)) << 4);

  for (int k0 = 0; k0 < 1024; k0 += 32) {
    const int half = k0 >> 9;              // 0: fwd cols, 1: bwd cols
    const size_t kb = (size_t)(k0 & 511) * 2;
    const char* Ah = (const char*)(obuf + ((size_t)(bB * 2 + half) << 12) * 512);
    const size_t ar0 = half ? (size_t)(4095 - (tbase + r0))      : (size_t)(tbase + r0);
    const size_t ar1 = half ? (size_t)(4095 - (tbase + r0 + 64)) : (size_t)(tbase + r0 + 64);
    gload_lds16(Ah + ar0 * 1024 + kb + cb, (char*)As + tid * 16);
    gload_lds16(Ah + ar1 * 1024 + kb + cb, (char*)As + 4096 + tid * 16);
    gload_lds16(Bb + (size_t)r0 * 2048 + (size_t)k0 * 2 + cb,        (char*)Bsm + tid * 16);
    gload_lds16(Bb + (size_t)(r0 + 64) * 2048 + (size_t)k0 * 2 + cb, (char*)Bsm + 4096 + tid * 16);
    __syncthreads();
    h8 af[4], bg[4];
    #pragma unroll
    for (int i = 0; i < 4; ++i) {
      const int ar = wr * 64 + i * 16 + ln15;
      const int br = wc * 64 + i * 16 + ln15;
      af[i] = *(const h8*)((char*)As  + ((ar * 4 + (lq ^ (ar & 3))) << 4));
      bg[i] = *(const h8*)((char*)Bsm + ((br * 4 + (lq ^ (br & 3))) << 4));
    }
    #pragma unroll
    for (int i = 0; i < 4; ++i)
      #pragma unroll
      for (int j = 0; j < 4; ++j)
        acc[i][j] = __builtin_amdgcn_mfma_f32_16x16x32_f16(af[i], bg[j], acc[i][j], 0, 0, 0);
    __syncthreads();
  }

  const int tq = tid >> 3, t8 = tid & 7;
  #pragma unroll
  for (int i = 0; i < 4; ++i) {
    __syncthreads();
    float* st = (float*)smem;
    #pragma unroll
    for (int j = 0; j < 4; ++j) {
      const int cl = wc * 64 + j * 16 + ln15;
      #pragma unroll
      for (int q = 0; q < 4; ++q) {
        const int rl = wr * 16 + lq * 4 + q;
        st[rl * 128 + (cl ^ (((rl >> 2) & 3) << 4))] = acc[i][j][q];
      }
    }
    __syncthreads();
    const int rl = tq, lqp = (rl >> 2) & 3;
    const int lr = ((rl >> 4) << 6) + (i << 4) + (rl & 15);
    const int rowg = (int)m0 + lr;
    #pragma unroll
    for (int u = 0; u < 4; ++u) {
      const int colL = t8 * 16 + u * 4;
      const int colS = colL ^ (lqp << 4);
      f4 vv = *(const f4*)(st + rl * 128 + colS);
      *(f4*)(out + (size_t)rowg * 512 + n0 + colL) = vv;
    }
  }
}

// ---------- WKV chunked scan (NCH2=256 parallelism, h8 16B loads) ----------
// pass1: per-chunk local end-state. block (64,2): 2 chunks/block, 8 ch/thread.
__global__ __launch_bounds__(128)
void wkv_pass1(const _Float16* __restrict__ kbuf, const _Float16* __restrict__ vbuf,
               const float* __restrict__ td, const float* __restrict__ tdr,
               float* __restrict__ cN, float* __restrict__ cD, float* __restrict__ cM) {
  const int bd = blockIdx.x;
  const int ch = blockIdx.y * 2 + threadIdx.y;
  const int dir = bd & 1;
  const int c = threadIdx.x * 8;
  const float* tdp = (dir ? tdr : td) + c;
  float w[8], num[8], den[8], m[8];
  #pragma unroll
  for (int e = 0; e < 8; ++e) { w[e] = -__expf(tdp[e]); num[e] = 0.f; den[e] = 0.f; m[e] = -1e38f; }
  const size_t base = ((size_t)bd * TT + (size_t)ch * CHL2) * CCH + c;
  const _Float16* kp = kbuf + base;
  const _Float16* vp = vbuf + base;
  h8 ka = *(const h8*)(kp), va = *(const h8*)(vp);
  h8 kb = *(const h8*)(kp + CCH), vb = *(const h8*)(vp + CCH);
  for (int t = 0; t < CHL2; ++t) {
    h8 kc = {}, vc = {};
    if (t + 2 < CHL2) {
      kc = *(const h8*)(kp + (size_t)(t + 2) * CCH);
      vc = *(const h8*)(vp + (size_t)(t + 2) * CCH);
    }
    #pragma unroll
    for (int e = 0; e < 8; ++e) {
      float ke = (float)ka[e], ve = (float)va[e];
      float mw = m[e] + w[e];
      float m2 = fmaxf(mw, ke);
      float e1 = __expf(mw - m2), e2 = __expf(ke - m2);
      num[e] = e1 * num[e] + e2 * ve;
      den[e] = e1 * den[e] + e2;
      m[e] = m2;
    }
    ka = kb; va = vb; kb = kc; vb = vc;
  }
  const size_t ci = ((size_t)bd * NCH2 + ch) * CCH + c;
  #pragma unroll
  for (int h = 0; h < 2; ++h) {
    *(f4*)(cN + ci + h * 4) = (f4){num[h*4], num[h*4+1], num[h*4+2], num[h*4+3]};
    *(f4*)(cD + ci + h * 4) = (f4){den[h*4], den[h*4+1], den[h*4+2], den[h*4+3]};
    *(f4*)(cM + ci + h * 4) = (f4){m[h*4], m[h*4+1], m[h*4+2], m[h*4+3]};
  }
}

// pass2a: per-segment combine of SEGC chunk states -> segment carry
__global__ __launch_bounds__(128)
void wkv_p2a(const float* __restrict__ td, const float* __restrict__ tdr,
             const float* __restrict__ cN, const float* __restrict__ cD,
             const float* __restrict__ cM,
             float* __restrict__ scN, float* __restrict__ scD, float* __restrict__ scM) {
  const int bd = blockIdx.x, seg = blockIdx.y;
  const int dir = bd & 1;
  const int c = threadIdx.x * 4;
  f4 tdv = *(const f4*)((dir ? tdr : td) + c);
  float dw[4], num[4], den[4], m[4];
  #pragma unroll
  for (int e = 0; e < 4; ++e) { dw[e] = -__expf(tdv[e]) * (float)CHL2; num[e] = 0.f; den[e] = 0.f; m[e] = -1e38f; }
  size_t ci = ((size_t)bd * NCH2 + (size_t)seg * SEGC) * CCH + c;
  for (int j = 0; j < SEGC; ++j, ci += CCH) {
    f4 ln = *(const f4*)(cN + ci);
    f4 ld = *(const f4*)(cD + ci);
    f4 lm = *(const f4*)(cM + ci);
    #pragma unroll
    for (int e = 0; e < 4; ++e) {
      float mp = m[e] + dw[e];
      float mm = fmaxf(mp, lm[e]);
      float e1 = __expf(mp - mm), e2 = __expf(lm[e] - mm);
      num[e] = e1 * num[e] + e2 * ln[e];
      den[e] = e1 * den[e] + e2 * ld[e];
      m[e] = mm;
    }
  }
  const size_t si = ((size_t)bd * NSEG + seg) * CCH + c;
  *(f4*)(scN + si) = (f4){num[0], num[1], num[2], num[3]};
  *(f4*)(scD + si) = (f4){den[0], den[1], den[2], den[3]};
  *(f4*)(scM + si) = (f4){m[0], m[1], m[2], m[3]};
}

// pass2b: serial exclusive scan over NSEG segment carries (rewrites in place)
__global__ __launch_bounds__(128)
void wkv_p2b(const float* __restrict__ td, const float* __restrict__ tdr,
             float* __restrict__ scN, float* __restrict__ scD, float* __restrict__ scM) {
  const int bd = blockIdx.x;
  const int dir = bd & 1;
  const int c = threadIdx.x * 4;
  f4 tdv = *(const f4*)((dir ? tdr : td) + c);
  float dws[4], num[4], den[4], m[4];
  #pragma unroll
  for (int e = 0; e < 4; ++e) { dws[e] = -__expf(tdv[e]) * (float)(CHL2 * SEGC); num[e] = 0.f; den[e] = 0.f; m[e] = -1e38f; }
  size_t si = (size_t)bd * NSEG * CCH + c;
  for (int s = 0; s < NSEG; ++s, si += CCH) {
    f4 ln = *(const f4*)(scN + si);
    f4 ld = *(const f4*)(scD + si);
    f4 lm = *(const f4*)(scM + si);
    *(f4*)(scN + si) = (f4){num[0], num[1], num[2], num[3]};
    *(f4*)(scD + si) = (f4){den[0], den[1], den[2], den[3]};
    *(f4*)(scM + si) = (f4){m[0], m[1], m[2], m[3]};
    #pragma unroll
    for (int e = 0; e < 4; ++e) {
      float mp = m[e] + dws[e];
      float mm = fmaxf(mp, lm[e]);
      float e1 = __expf(mp - mm), e2 = __expf(lm[e] - mm);
      num[e] = e1 * num[e] + e2 * ln[e];
      den[e] = e1 * den[e] + e2 * ld[e];
      m[e] = mm;
    }
  }
}

// pass2c: replay each segment from its exclusive prefix, rewriting chunk slots
__global__ __launch_bounds__(128)
void wkv_p2c(const float* __restrict__ td, const float* __restrict__ tdr,
             const float* __restrict__ scN, const float* __restrict__ scD,
             const float* __restrict__ scM,
             float* __restrict__ cN, float* __restrict__ cD, float* __restrict__ cM) {
  const int bd = blockIdx.x, seg = blockIdx.y;
  const int dir = bd & 1;
  const int c = threadIdx.x * 4;
  f4 tdv = *(const f4*)((dir ? tdr : td) + c);
  const size_t si = ((size_t)bd * NSEG + seg) * CCH + c;
  f4 nv = *(const f4*)(scN + si);
  f4 dv = *(const f4*)(scD + si);
  f4 mv = *(const f4*)(scM + si);
  float dw[4], num[4], den[4], m[4];
  #pragma unroll
  for (int e = 0; e < 4; ++e) {
    dw[e] = -__expf(tdv[e]) * (float)CHL2;
    num[e] = nv[e]; den[e] = dv[e]; m[e] = mv[e];
  }
  size_t ci = ((size_t)bd * NCH2 + (size_t)seg * SEGC) * CCH + c;
  for (int j = 0; j < SEGC; ++j, ci += CCH) {
    f4 ln = *(const f4*)(cN + ci);
    f4 ld = *(const f4*)(cD + ci);
    f4 lm = *(const f4*)(cM + ci);
    *(f4*)(cN + ci) = (f4){num[0], num[1], num[2], num[3]};
    *(f4*)(cD + ci) = (f4){den[0], den[1], den[2], den[3]};
    *(f4*)(cM + ci) = (f4){m[0], m[1], m[2], m[3]};
    #pragma unroll
    for (int e = 0; e < 4; ++e) {
      float mp = m[e] + dw[e];
      float mm = fmaxf(mp, lm[e]);
      float e1 = __expf(mp - mm), e2 = __expf(lm[e] - mm);
      num[e] = e1 * num[e] + e2 * ln[e];
      den[e] = e1 * den[e] + e2 * ld[e];
      m[e] = mm;
    }
  }
}

// pass3: replay each chunk from its carry, o = sigmoid(r)*y OVERWRITES rbuf in place
// (scan order; no index transform). block (64,2), 8 ch/thread.
__global__ __launch_bounds__(128)
void wkv_pass3(const _Float16* __restrict__ kbuf, const _Float16* __restrict__ vbuf,
               _Float16* __restrict__ rbuf,
               const float* __restrict__ td, const float* __restrict__ tf,
               const float* __restrict__ tdr, const float* __restrict__ tfr,
               const float* __restrict__ cN, const float* __restrict__ cD,
               const float* __restrict__ cM) {
  const int bd = blockIdx.x;
  const int ch = blockIdx.y * 2 + threadIdx.y;
  const int dir = bd & 1;
  const int c = threadIdx.x * 8;
  const float* tdp = (dir ? tdr : td) + c;
  const float* tup = (dir ? tfr : tf) + c;
  const size_t ci = ((size_t)bd * NCH2 + ch) * CCH + c;
  float w[8], u[8], num[8], den[8], m[8];
  #pragma unroll
  for (int e = 0; e < 8; ++e) {
    w[e] = -__expf(tdp[e]); u[e] = tup[e];
    num[e] = cN[ci + e]; den[e] = cD[ci + e]; m[e] = cM[ci + e];
  }
  const size_t base = ((size_t)bd * TT + (size_t)ch * CHL2) * CCH + c;
  const _Float16* kp = kbuf + base;
  const _Float16* vp = vbuf + base;
  _Float16* rp = rbuf + base;
  h8 ka = *(const h8*)(kp), va = *(const h8*)(vp), ra = *(const h8*)(rp);
  h8 kb = *(const h8*)(kp + CCH), vb = *(const h8*)(vp + CCH), rb = *(const h8*)(rp + CCH);
  for (int t = 0; t < CHL2; ++t) {
    h8 kc = {}, vc = {}, rc = {};
    if (t + 2 < CHL2) {
      kc = *(const h8*)(kp + (size_t)(t + 2) * CCH);
      vc = *(const h8*)(vp + (size_t)(t + 2) * CCH);
      rc = *(const h8*)(rp + (size_t)(t + 2) * CCH);
    }
    _Float16 o[8];
    #pragma unroll
    for (int e = 0; e < 8; ++e) {
      float ke = (float)ka[e], ve = (float)va[e];
      float ku = ke + u[e];
      float mm = fmaxf(m[e], ku);
      float e1 = __expf(m[e] - mm), e2 = __expf(ku - mm);
      float y = (e1 * num[e] + e2 * ve) * __builtin_amdgcn_rcpf(e1 * den[e] + e2);
      float rt = (float)ra[e];
      float sig = __builtin_amdgcn_rcpf(1.f + __expf(-rt));
      o[e] = (_Float16)(sig * y);
      float mw = m[e] + w[e];
      float m2 = fmaxf(mw, ke);
      float es1 = __expf(mw - m2), es2 = __expf(ke - m2);
      num[e] = es1 * num[e] + es2 * ve;
      den[e] = es1 * den[e] + es2;
      m[e] = m2;
    }
    h8 ov = { o[0], o[1], o[2], o[3], o[4], o[5], o[6], o[7] };
    *(h8*)(rp + (size_t)t * CCH) = ov;   // overwrite r with o in place
    ka = kb; va = vb; ra = rb; kb = kc; vb = vc; rb = rc;
  }
}

// ---------- launch ----------
extern "C" void kernel_launch(void* const* d_in, const int* in_sizes, int n_in,
                              void* d_out, int out_size, void* d_ws, size_t ws_size,
                              hipStream_t stream) {
  const float* x   = (const float*)d_in[0];
  const float* Wr  = (const float*)d_in[1];
  const float* Wo  = (const float*)d_in[2];
  const float* td  = (const float*)d_in[3];
  const float* tf  = (const float*)d_in[4];
  const float* tdr = (const float*)d_in[5];
  const float* tfr = (const float*)d_in[6];
  float* out = (float*)d_out;

  auto rnd = [](size_t b) { return (b + 255) & ~(size_t)255; };
  const size_t wBytes = rnd((size_t)3072 * 512 * 2) + rnd((size_t)512 * 1024 * 2);
  // k, v, r (f16) + xb (bf16; carries alias into xb after GEMM1 consumes it).
  // carry bytes = 3*(Bs*2*NCH2*512*4) + 3*(Bs*2*NSEG*512*4) = 3.375*Bs MiB <= xb's 4*Bs MiB.
  auto need = [&](int Bs) {
    size_t s = wBytes;
    s += 3 * rnd((size_t)Bs * 2 * TT * 512 * 2);
    s += rnd((size_t)Bs * TT * 512 * 2);
    return s;
  };
  int Bs = 8;
  while (Bs > 1 && need(Bs) > ws_size) Bs >>= 1;

  char* ws = (char*)d_ws;
  size_t off = 0;
  auto alloc = [&](size_t bytes) -> char* {
    char* p = ws + off;
    off += (bytes + 255) & ~(size_t)255;
    return p;
  };
  unsigned short* wrkvT = (unsigned short*)alloc((size_t)3072 * 512 * 2);
  _Float16*       woutT = (_Float16*)alloc((size_t)512 * 1024 * 2);
  _Float16*       kbuf  = (_Float16*)alloc((size_t)Bs * 2 * TT * 512 * 2);
  _Float16*       vbuf  = (_Float16*)alloc((size_t)Bs * 2 * TT * 512 * 2);
  _Float16*       rbuf  = (_Float16*)alloc((size_t)Bs * 2 * TT * 512 * 2);
  unsigned short* xb    = (unsigned short*)alloc((size_t)Bs * TT * 512 * 2);
  // carries live inside xb (xb is dead after GEMM1 reads it)
  const size_t cs = (size_t)Bs * 2 * NCH2 * 512;   // floats per chunk-carry array
  const size_t ss = (size_t)Bs * 2 * NSEG * 512;   // floats per seg-carry array
  float* cN  = (float*)xb;
  float* cD  = cN + cs;
  float* cM  = cD + cs;
  float* scN = cM + cs;
  float* scD = scN + ss;
  float* scM = scD + ss;

  transpose_to_bf16<<<dim3(3072 / 32, 512 / 32), dim3(32, 8), 0, stream>>>(Wr, wrkvT, 512, 3072);
  transpose_to_f16<<<dim3(512 / 32, 1024 / 32), dim3(32, 8), 0, stream>>>(Wo, woutT, 1024, 512);

  const int nslices = 8 / Bs;
  const int Mslice = Bs * TT;
  const int mt256 = Mslice >> 8;
  const int mt128 = Mslice >> 7;
  for (int s = 0; s < nslices; ++s) {
    const float* xs = x + (size_t)s * Mslice * 512;
    float* outs = out + (size_t)s * Mslice * 512;
    // 1. convert x slice to bf16 (into xb)
    convert_f32_bf16<<<Mslice * 512 / 1024, 256, 0, stream>>>(xs, xb, Mslice * 512 / 4);
    // 2. GEMM1 (256^2 pipelined): rkv = x @ W_rkv -> k/v/r (f16), bwd pre-reversed
    gemm256_g1<<<mt256 * 12, 512, 0, stream>>>(xb, wrkvT, kbuf, vbuf, rbuf);
    // 3. WKV chunked scan (carries overwrite xb region — xb is dead now)
    wkv_pass1<<<dim3(Bs * 2, NCH2 / 2), dim3(64, 2), 0, stream>>>(kbuf, vbuf, td, tdr, cN, cD, cM);
    wkv_p2a<<<dim3(Bs * 2, NSEG), 128, 0, stream>>>(td, tdr, cN, cD, cM, scN, scD, scM);
    wkv_p2b<<<Bs * 2, 128, 0, stream>>>(td, tdr, scN, scD, scM);
    wkv_p2c<<<dim3(Bs * 2, NSEG), 128, 0, stream>>>(td, tdr, scN, scD, scM, cN, cD, cM);
    wkv_pass3<<<dim3(Bs * 2, NCH2 / 2), dim3(64, 2), 0, stream>>>(kbuf, vbuf, rbuf, td, tf, tdr, tfr,
                                                                  cN, cD, cM);
    // 4. GEMM2: out = [oF | oB(rev)] @ W_out   (A = rbuf in place, f16 MFMA)
    gemm2_k<<<mt128 * 4, 256, 0, stream>>>(rbuf, woutT, Mslice, outs);
  }
}

// Round 13
// 300.941 us; speedup vs baseline: 1.4497x; 1.1109x over previous
//
#include <hip/hip_runtime.h>

// ---------- types ----------
typedef float f4 __attribute__((ext_vector_type(4)));
typedef unsigned short us4 __attribute__((ext_vector_type(4)));
typedef __bf16 bf16x8 __attribute__((ext_vector_type(8)));
typedef float f32x4 __attribute__((ext_vector_type(4)));
typedef _Float16 h8 __attribute__((ext_vector_type(8)));

#define TT 4096
#define CCH 512
#define NCH2 256      // chunks per sequence
#define CHL2 16       // timesteps per chunk (TT / NCH2)
#define NSEG 32       // segments for hierarchical pass2
#define SEGC 8        // chunks per segment (NCH2 / NSEG)

// ---------- helpers ----------
__device__ __forceinline__ unsigned short f2bf(float f) {
  unsigned u = __builtin_bit_cast(unsigned, f);
  unsigned r = (u + 0x7FFFu + ((u >> 16) & 1u)) >> 16;
  return (unsigned short)r;
}
__device__ __forceinline__ void gload_lds16(const void* g, void* l) {
  __builtin_amdgcn_global_load_lds(
      (const __attribute__((address_space(1))) unsigned int*)g,
      (__attribute__((address_space(3))) unsigned int*)l, 16, 0, 0);
}
#define VMCNT(n) asm volatile("s_waitcnt vmcnt(" #n ")" ::: "memory")

// ---------- convert x (f32 -> bf16), 4 elems/thread ----------
__global__ __launch_bounds__(256)
void convert_f32_bf16(const float* __restrict__ in, unsigned short* __restrict__ out, int n4) {
  int i = blockIdx.x * 256 + threadIdx.x;
  if (i >= n4) return;
  f4 f = *(const f4*)(in + (size_t)i * 4);
  us4 o = { f2bf(f[0]), f2bf(f[1]), f2bf(f[2]), f2bf(f[3]) };
  *(us4*)(out + (size_t)i * 4) = o;
}

// ---------- transpose+convert weights: in (R x Cc) f32 -> (Cc x R) bf16 ----------
__global__ __launch_bounds__(256)
void transpose_to_bf16(const float* __restrict__ in, unsigned short* __restrict__ out,
                       int R, int Cc) {
  __shared__ unsigned short tile[32][33];
  int c0 = blockIdx.x * 32, r0 = blockIdx.y * 32;
  int tx = threadIdx.x, ty = threadIdx.y;
  #pragma unroll
  for (int j = 0; j < 32; j += 8)
    tile[ty + j][tx] = f2bf(in[(size_t)(r0 + ty + j) * Cc + c0 + tx]);
  __syncthreads();
  #pragma unroll
  for (int j = 0; j < 32; j += 8)
    out[(size_t)(c0 + ty + j) * R + r0 + tx] = tile[tx][ty + j];
}

// ---------- transpose+convert weights: in (R x Cc) f32 -> (Cc x R) f16 ----------
__global__ __launch_bounds__(256)
void transpose_to_f16(const float* __restrict__ in, _Float16* __restrict__ out,
                      int R, int Cc) {
  __shared__ _Float16 tile[32][33];
  int c0 = blockIdx.x * 32, r0 = blockIdx.y * 32;
  int tx = threadIdx.x, ty = threadIdx.y;
  #pragma unroll
  for (int j = 0; j < 32; j += 8)
    tile[ty + j][tx] = (_Float16)in[(size_t)(r0 + ty + j) * Cc + c0 + tx];
  __syncthreads();
  #pragma unroll
  for (int j = 0; j < 32; j += 8)
    out[(size_t)(c0 + ty + j) * R + r0 + tx] = tile[tx][ty + j];
}

// ============ GEMM1: 256x256 tile, BK=64, 8 waves, counted-vmcnt pipeline ============
__global__ __launch_bounds__(512, 2)
void gemm256_g1(const unsigned short* __restrict__ A,
                const unsigned short* __restrict__ BT,
                _Float16* __restrict__ kbuf, _Float16* __restrict__ vbuf,
                _Float16* __restrict__ rbuf) {
  __shared__ char lds[131072];   // A: [0,65536) = 2 slots x 32 KiB; B: [65536,131072)
  const int tid = threadIdx.x;
  const int lane = tid & 63, wv = tid >> 6;
  const int wm = wv >> 2, wn = wv & 3;
  const int ln15 = lane & 15, lq = lane >> 4;

  const int nwg = gridDim.x;
  const int bid = blockIdx.x;
  const int wgid = (nwg % 8 == 0) ? (bid % 8) * (nwg / 8) + bid / 8 : bid;
  const int bn = wgid % 12, bm = wgid / 12;
  const size_t m0 = (size_t)bm * 256, n0 = (size_t)bn * 256;
  const char* Ab = (const char*)(A + m0 * 512);
  const char* Bb = (const char*)(BT + n0 * 512);

  const int srow0 = tid >> 2, srow1 = 128 + (tid >> 2);
  const int sg = tid & 3;
  const int sgs0 = (sg ^ ((srow0 >> 1) & 3)) << 4;
  const int sgs1 = (sg ^ ((srow1 >> 1) & 3)) << 4;

  auto STAGE = [&](int mat, int t, int h) {
    const char* gsrc = mat ? Bb : Ab;
    char* ldst = lds + mat * 65536 + ((t & 1) << 15) + (h << 14);
    const size_t co = (size_t)t * 128 + (size_t)h * 64;
    gload_lds16(gsrc + (size_t)srow0 * 1024 + co + sgs0, ldst + tid * 16);
    gload_lds16(gsrc + (size_t)srow1 * 1024 + co + sgs1, ldst + 8192 + tid * 16);
  };

  f32x4 acc[8][4] = {};
  STAGE(0, 0, 0); STAGE(1, 0, 0); STAGE(0, 0, 1); STAGE(1, 0, 1);

  for (int t = 0; t < 8; ++t) {
    char* Abase = lds + ((t & 1) << 15);
    char* Bbase = lds + 65536 + ((t & 1) << 15);
    // ---- super-phase A (ks = 0) ----
    VMCNT(4);
    __builtin_amdgcn_s_barrier();
    __builtin_amdgcn_sched_barrier(0);
    {
      bf16x8 bf[4], af[8];
      #pragma unroll
      for (int fn = 0; fn < 4; ++fn) {
        const int r = wn * 64 + fn * 16 + ln15;
        bf[fn] = *(const bf16x8*)(Bbase + r * 64 + ((lq ^ ((r >> 1) & 3)) << 4));
      }
      #pragma unroll
      for (int fm = 0; fm < 8; ++fm) {
        const int r = wm * 128 + fm * 16 + ln15;
        af[fm] = *(const bf16x8*)(Abase + r * 64 + ((lq ^ ((r >> 1) & 3)) << 4));
      }
      if (t < 7) { STAGE(0, t + 1, 0); STAGE(1, t + 1, 0); }
      __builtin_amdgcn_s_setprio(1);
      #pragma unroll
      for (int fm = 0; fm < 8; ++fm)
        #pragma unroll
        for (int fn = 0; fn < 4; ++fn)
          acc[fm][fn] = __builtin_amdgcn_mfma_f32_16x16x32_bf16(af[fm], bf[fn], acc[fm][fn], 0, 0, 0);
      __builtin_amdgcn_s_setprio(0);
    }
    // ---- super-phase B (ks = 1) ----
    if (t < 7) { VMCNT(4); } else { VMCNT(0); }
    __builtin_amdgcn_s_barrier();
    __builtin_amdgcn_sched_barrier(0);
    {
      bf16x8 bf[4], af[8];
      #pragma unroll
      for (int fn = 0; fn < 4; ++fn) {
        const int r = wn * 64 + fn * 16 + ln15;
        bf[fn] = *(const bf16x8*)(Bbase + 16384 + r * 64 + ((lq ^ ((r >> 1) & 3)) << 4));
      }
      #pragma unroll
      for (int fm = 0; fm < 8; ++fm) {
        const int r = wm * 128 + fm * 16 + ln15;
        af[fm] = *(const bf16x8*)(Abase + 16384 + r * 64 + ((lq ^ ((r >> 1) & 3)) << 4));
      }
      if (t < 7) { STAGE(0, t + 1, 1); STAGE(1, t + 1, 1); }
      __builtin_amdgcn_s_setprio(1);
      #pragma unroll
      for (int fm = 0; fm < 8; ++fm)
        #pragma unroll
        for (int fn = 0; fn < 4; ++fn)
          acc[fm][fn] = __builtin_amdgcn_mfma_f32_16x16x32_bf16(af[fm], bf[fn], acc[fm][fn], 0, 0, 0);
      __builtin_amdgcn_s_setprio(0);
    }
  }

  // ---- epilogue: LDS-staged coalesced f16 stores ----
  const int n0i = (int)n0;
  const int dir = (n0i >= 1536) ? 1 : 0;
  const int jj0 = n0i - dir * 1536;
  const int seg = jj0 >> 9;
  const int cbase = jj0 & 511;           // 0 or 256
  _Float16* dbuf = (seg == 0) ? rbuf : (seg == 1 ? kbuf : vbuf);
  float* stg = (float*)lds;              // [2][32][256] f32 (64 KiB)
  const int ebnd = wv >> 2;              // == wm
  const int erow = (tid >> 3) & 31;
  const int el8 = tid & 7;
  __syncthreads();
  #pragma unroll
  for (int gi = 0; gi < 4; ++gi) {
    #pragma unroll
    for (int f2 = 0; f2 < 2; ++f2) {
      const int fm = gi * 2 + f2;
      #pragma unroll
      for (int q = 0; q < 4; ++q) {
        const int rloc = f2 * 16 + lq * 4 + q;
        float* dst = stg + wm * 8192 + rloc * 256;
        const int sw = ((rloc >> 2) & 1) << 4;
        #pragma unroll
        for (int fn = 0; fn < 4; ++fn)
          dst[(wn * 64 + fn * 16 + ln15) ^ sw] = acc[fm][fn][q];
      }
    }
    __syncthreads();
    {
      const int rowg = (int)m0 + ebnd * 128 + gi * 32 + erow;
      const int b_ = rowg >> 12, tt = rowg & 4095;
      const int trow = dir ? (4095 - tt) : tt;
      _Float16* gp = dbuf + ((size_t)(b_ * 2 + dir) * TT + trow) * 512 + cbase;
      const float* sp = stg + ebnd * 8192 + erow * 256;
      const int sw = ((erow >> 2) & 1) << 4;
      #pragma unroll
      for (int u = 0; u < 4; ++u) {
        const int cf = el8 * 8 + u * 64;
        const int cs = cf ^ sw;
        f4 a = *(const f4*)(sp + cs);
        f4 b = *(const f4*)(sp + cs + 4);
        h8 hv = { (_Float16)a[0], (_Float16)a[1], (_Float16)a[2], (_Float16)a[3],
                  (_Float16)b[0], (_Float16)b[1], (_Float16)b[2], (_Float16)b[3] };
        *(h8*)(gp + cf) = hv;
      }
    }
    __syncthreads();
  }
}

// ============ GEMM2: 256x256 tile, BK=64, counted-vmcnt, f16, two-half A ============
// A row (b*4096+t): cols 0-511 = obuf[b][0][t][:] (fwd, natural),
//                   cols 512-1023 = obuf[b][1][4095-t][:] (bwd, scan order).
// Row reversal folded into the per-lane stage SOURCE address (LDS stays linear).
__global__ __launch_bounds__(512, 2)
void gemm2_256(const _Float16* __restrict__ obuf,
               const _Float16* __restrict__ BT,   // woutT: 512 x 1024 f16 (N x K)
               float* __restrict__ out) {
  __shared__ char lds[131072];
  const int tid = threadIdx.x;
  const int lane = tid & 63, wv = tid >> 6;
  const int wm = wv >> 2, wn = wv & 3;
  const int ln15 = lane & 15, lq = lane >> 4;

  const int nwg = gridDim.x;
  const int bid = blockIdx.x;
  const int wgid = (nwg % 8 == 0) ? (bid % 8) * (nwg / 8) + bid / 8 : bid;
  const int bn = wgid % 2, bm = wgid / 2;
  const size_t m0 = (size_t)bm * 256, n0 = (size_t)bn * 256;
  const int bB = (int)(m0 >> 12);        // batch (256-row tile never crosses batch)
  const int tbase = (int)(m0 & 4095);
  const char* Bb = (const char*)(BT + n0 * 1024);

  const int srow0 = tid >> 2, srow1 = 128 + (tid >> 2);
  const int sg = tid & 3;
  const int sgs0 = (sg ^ ((srow0 >> 1) & 3)) << 4;
  const int sgs1 = (sg ^ ((srow1 >> 1) & 3)) << 4;

  // stage K-half h of K-tile t (t in [0,16)); A half flips at t==8
  auto STAGE = [&](int mat, int t, int h) {
    char* ldst = lds + mat * 65536 + ((t & 1) << 15) + (h << 14);
    if (mat == 0) {
      const int half = t >> 3;
      const char* Ah = (const char*)(obuf + (((size_t)(bB * 2 + half)) << 12) * 512);
      const size_t co = (size_t)(t & 7) * 128 + (size_t)h * 64;
      const size_t ar0 = half ? (size_t)(4095 - (tbase + srow0)) : (size_t)(tbase + srow0);
      const size_t ar1 = half ? (size_t)(4095 - (tbase + srow1)) : (size_t)(tbase + srow1);
      gload_lds16(Ah + ar0 * 1024 + co + sgs0, ldst + tid * 16);
      gload_lds16(Ah + ar1 * 1024 + co + sgs1, ldst + 8192 + tid * 16);
    } else {
      const size_t co = (size_t)t * 128 + (size_t)h * 64;
      gload_lds16(Bb + (size_t)srow0 * 2048 + co + sgs0, ldst + tid * 16);
      gload_lds16(Bb + (size_t)srow1 * 2048 + co + sgs1, ldst + 8192 + tid * 16);
    }
  };

  f32x4 acc[8][4] = {};
  STAGE(0, 0, 0); STAGE(1, 0, 0); STAGE(0, 0, 1); STAGE(1, 0, 1);

  for (int t = 0; t < 16; ++t) {
    char* Abase = lds + ((t & 1) << 15);
    char* Bbase = lds + 65536 + ((t & 1) << 15);
    // ---- super-phase A (ks = 0) ----
    VMCNT(4);
    __builtin_amdgcn_s_barrier();
    __builtin_amdgcn_sched_barrier(0);
    {
      h8 bf[4], af[8];
      #pragma unroll
      for (int fn = 0; fn < 4; ++fn) {
        const int r = wn * 64 + fn * 16 + ln15;
        bf[fn] = *(const h8*)(Bbase + r * 64 + ((lq ^ ((r >> 1) & 3)) << 4));
      }
      #pragma unroll
      for (int fm = 0; fm < 8; ++fm) {
        const int r = wm * 128 + fm * 16 + ln15;
        af[fm] = *(const h8*)(Abase + r * 64 + ((lq ^ ((r >> 1) & 3)) << 4));
      }
      if (t < 15) { STAGE(0, t + 1, 0); STAGE(1, t + 1, 0); }
      __builtin_amdgcn_s_setprio(1);
      #pragma unroll
      for (int fm = 0; fm < 8; ++fm)
        #pragma unroll
        for (int fn = 0; fn < 4; ++fn)
          acc[fm][fn] = __builtin_amdgcn_mfma_f32_16x16x32_f16(af[fm], bf[fn], acc[fm][fn], 0, 0, 0);
      __builtin_amdgcn_s_setprio(0);
    }
    // ---- super-phase B (ks = 1) ----
    if (t < 15) { VMCNT(4); } else { VMCNT(0); }
    __builtin_amdgcn_s_barrier();
    __builtin_amdgcn_sched_barrier(0);
    {
      h8 bf[4], af[8];
      #pragma unroll
      for (int fn = 0; fn < 4; ++fn) {
        const int r = wn * 64 + fn * 16 + ln15;
        bf[fn] = *(const h8*)(Bbase + 16384 + r * 64 + ((lq ^ ((r >> 1) & 3)) << 4));
      }
      #pragma unroll
      for (int fm = 0; fm < 8; ++fm) {
        const int r = wm * 128 + fm * 16 + ln15;
        af[fm] = *(const h8*)(Abase + 16384 + r * 64 + ((lq ^ ((r >> 1) & 3)) << 4));
      }
      if (t < 15) { STAGE(0, t + 1, 1); STAGE(1, t + 1, 1); }
      __builtin_amdgcn_s_setprio(1);
      #pragma unroll
      for (int fm = 0; fm < 8; ++fm)
        #pragma unroll
        for (int fn = 0; fn < 4; ++fn)
          acc[fm][fn] = __builtin_amdgcn_mfma_f32_16x16x32_f16(af[fm], bf[fn], acc[fm][fn], 0, 0, 0);
      __builtin_amdgcn_s_setprio(0);
    }
  }

  // ---- epilogue: LDS-staged coalesced f32 stores ----
  float* stg = (float*)lds;              // [2][32][256] f32 (64 KiB)
  const int ebnd = wv >> 2;
  const int erow = (tid >> 3) & 31;
  const int el8 = tid & 7;
  __syncthreads();
  #pragma unroll
  for (int gi = 0; gi < 4; ++gi) {
    #pragma unroll
    for (int f2 = 0; f2 < 2; ++f2) {
      const int fm = gi * 2 + f2;
      #pragma unroll
      for (int q = 0; q < 4; ++q) {
        const int rloc = f2 * 16 + lq * 4 + q;
        float* dst = stg + wm * 8192 + rloc * 256;
        const int sw = ((rloc >> 2) & 1) << 4;
        #pragma unroll
        for (int fn = 0; fn < 4; ++fn)
          dst[(wn * 64 + fn * 16 + ln15) ^ sw] = acc[fm][fn][q];
      }
    }
    __syncthreads();
    {
      const int rowg = (int)m0 + ebnd * 128 + gi * 32 + erow;
      float* gp = out + (size_t)rowg * 512 + n0;
      const float* sp = stg + ebnd * 8192 + erow * 256;
      const int sw = ((erow >> 2) & 1) << 4;
      #pragma unroll
      for (int u = 0; u < 4; ++u) {
        const int cf = el8 * 8 + u * 64;
        const int cs = cf ^ sw;
        f4 a = *(const f4*)(sp + cs);
        f4 b = *(const f4*)(sp + cs + 4);
        *(f4*)(gp + cf) = a;
        *(f4*)(gp + cf + 4) = b;
      }
    }
    __syncthreads();
  }
}

// ---------- WKV chunked scan (NCH2=256 parallelism, h8 16B loads) ----------
__global__ __launch_bounds__(128)
void wkv_pass1(const _Float16* __restrict__ kbuf, const _Float16* __restrict__ vbuf,
               const float* __restrict__ td, const float* __restrict__ tdr,
               float* __restrict__ cN, float* __restrict__ cD, float* __restrict__ cM) {
  const int bd = blockIdx.x;
  const int ch = blockIdx.y * 2 + threadIdx.y;
  const int dir = bd & 1;
  const int c = threadIdx.x * 8;
  const float* tdp = (dir ? tdr : td) + c;
  float w[8], num[8], den[8], m[8];
  #pragma unroll
  for (int e = 0; e < 8; ++e) { w[e] = -__expf(tdp[e]); num[e] = 0.f; den[e] = 0.f; m[e] = -1e38f; }
  const size_t base = ((size_t)bd * TT + (size_t)ch * CHL2) * CCH + c;
  const _Float16* kp = kbuf + base;
  const _Float16* vp = vbuf + base;
  h8 ka = *(const h8*)(kp), va = *(const h8*)(vp);
  h8 kb = *(const h8*)(kp + CCH), vb = *(const h8*)(vp + CCH);
  for (int t = 0; t < CHL2; ++t) {
    h8 kc = {}, vc = {};
    if (t + 2 < CHL2) {
      kc = *(const h8*)(kp + (size_t)(t + 2) * CCH);
      vc = *(const h8*)(vp + (size_t)(t + 2) * CCH);
    }
    #pragma unroll
    for (int e = 0; e < 8; ++e) {
      float ke = (float)ka[e], ve = (float)va[e];
      float mw = m[e] + w[e];
      float m2 = fmaxf(mw, ke);
      float e1 = __expf(mw - m2), e2 = __expf(ke - m2);
      num[e] = e1 * num[e] + e2 * ve;
      den[e] = e1 * den[e] + e2;
      m[e] = m2;
    }
    ka = kb; va = vb; kb = kc; vb = vc;
  }
  const size_t ci = ((size_t)bd * NCH2 + ch) * CCH + c;
  #pragma unroll
  for (int h = 0; h < 2; ++h) {
    *(f4*)(cN + ci + h * 4) = (f4){num[h*4], num[h*4+1], num[h*4+2], num[h*4+3]};
    *(f4*)(cD + ci + h * 4) = (f4){den[h*4], den[h*4+1], den[h*4+2], den[h*4+3]};
    *(f4*)(cM + ci + h * 4) = (f4){m[h*4], m[h*4+1], m[h*4+2], m[h*4+3]};
  }
}

__global__ __launch_bounds__(128)
void wkv_p2a(const float* __restrict__ td, const float* __restrict__ tdr,
             const float* __restrict__ cN, const float* __restrict__ cD,
             const float* __restrict__ cM,
             float* __restrict__ scN, float* __restrict__ scD, float* __restrict__ scM) {
  const int bd = blockIdx.x, seg = blockIdx.y;
  const int dir = bd & 1;
  const int c = threadIdx.x * 4;
  f4 tdv = *(const f4*)((dir ? tdr : td) + c);
  float dw[4], num[4], den[4], m[4];
  #pragma unroll
  for (int e = 0; e < 4; ++e) { dw[e] = -__expf(tdv[e]) * (float)CHL2; num[e] = 0.f; den[e] = 0.f; m[e] = -1e38f; }
  size_t ci = ((size_t)bd * NCH2 + (size_t)seg * SEGC) * CCH + c;
  for (int j = 0; j < SEGC; ++j, ci += CCH) {
    f4 ln = *(const f4*)(cN + ci);
    f4 ld = *(const f4*)(cD + ci);
    f4 lm = *(const f4*)(cM + ci);
    #pragma unroll
    for (int e = 0; e < 4; ++e) {
      float mp = m[e] + dw[e];
      float mm = fmaxf(mp, lm[e]);
      float e1 = __expf(mp - mm), e2 = __expf(lm[e] - mm);
      num[e] = e1 * num[e] + e2 * ln[e];
      den[e] = e1 * den[e] + e2 * ld[e];
      m[e] = mm;
    }
  }
  const size_t si = ((size_t)bd * NSEG + seg) * CCH + c;
  *(f4*)(scN + si) = (f4){num[0], num[1], num[2], num[3]};
  *(f4*)(scD + si) = (f4){den[0], den[1], den[2], den[3]};
  *(f4*)(scM + si) = (f4){m[0], m[1], m[2], m[3]};
}

__global__ __launch_bounds__(128)
void wkv_p2b(const float* __restrict__ td, const float* __restrict__ tdr,
             float* __restrict__ scN, float* __restrict__ scD, float* __restrict__ scM) {
  const int bd = blockIdx.x;
  const int dir = bd & 1;
  const int c = threadIdx.x * 4;
  f4 tdv = *(const f4*)((dir ? tdr : td) + c);
  float dws[4], num[4], den[4], m[4];
  #pragma unroll
  for (int e = 0; e < 4; ++e) { dws[e] = -__expf(tdv[e]) * (float)(CHL2 * SEGC); num[e] = 0.f; den[e] = 0.f; m[e] = -1e38f; }
  size_t si = (size_t)bd * NSEG * CCH + c;
  for (int s = 0; s < NSEG; ++s, si += CCH) {
    f4 ln = *(const f4*)(scN + si);
    f4 ld = *(const f4*)(scD + si);
    f4 lm = *(const f4*)(scM + si);
    *(f4*)(scN + si) = (f4){num[0], num[1], num[2], num[3]};
    *(f4*)(scD + si) = (f4){den[0], den[1], den[2], den[3]};
    *(f4*)(scM + si) = (f4){m[0], m[1], m[2], m[3]};
    #pragma unroll
    for (int e = 0; e < 4; ++e) {
      float mp = m[e] + dws[e];
      float mm = fmaxf(mp, lm[e]);
      float e1 = __expf(mp - mm), e2 = __expf(lm[e] - mm);
      num[e] = e1 * num[e] + e2 * ln[e];
      den[e] = e1 * den[e] + e2 * ld[e];
      m[e] = mm;
    }
  }
}

__global__ __launch_bounds__(128)
void wkv_p2c(const float* __restrict__ td, const float* __restrict__ tdr,
             const float* __restrict__ scN, const float* __restrict__ scD,
             const float* __restrict__ scM,
             float* __restrict__ cN, float* __restrict__ cD, float* __restrict__ cM) {
  const int bd = blockIdx.x, seg = blockIdx.y;
  const int dir = bd & 1;
  const int c = threadIdx.x * 4;
  f4 tdv = *(const f4*)((dir ? tdr : td) + c);
  const size_t si = ((size_t)bd * NSEG + seg) * CCH + c;
  f4 nv = *(const f4*)(scN + si);
  f4 dv = *(const f4*)(scD + si);
  f4 mv = *(const f4*)(scM + si);
  float dw[4], num[4], den[4], m[4];
  #pragma unroll
  for (int e = 0; e < 4; ++e) {
    dw[e] = -__expf(tdv[e]) * (float)CHL2;
    num[e] = nv[e]; den[e] = dv[e]; m[e] = mv[e];
  }
  size_t ci = ((size_t)bd * NCH2 + (size_t)seg * SEGC) * CCH + c;
  for (int j = 0; j < SEGC; ++j, ci += CCH) {
    f4 ln = *(const f4*)(cN + ci);
    f4 ld = *(const f4*)(cD + ci);
    f4 lm = *(const f4*)(cM + ci);
    *(f4*)(cN + ci) = (f4){num[0], num[1], num[2], num[3]};
    *(f4*)(cD + ci) = (f4){den[0], den[1], den[2], den[3]};
    *(f4*)(cM + ci) = (f4){m[0], m[1], m[2], m[3]};
    #pragma unroll
    for (int e = 0; e < 4; ++e) {
      float mp = m[e] + dw[e];
      float mm = fmaxf(mp, lm[e]);
      float e1 = __expf(mp - mm), e2 = __expf(lm[e] - mm);
      num[e] = e1 * num[e] + e2 * ln[e];
      den[e] = e1 * den[e] + e2 * ld[e];
      m[e] = mm;
    }
  }
}

// pass3: replay each chunk from its carry, o = sigmoid(r)*y OVERWRITES rbuf in place
__global__ __launch_bounds__(128)
void wkv_pass3(const _Float16* __restrict__ kbuf, const _Float16* __restrict__ vbuf,
               _Float16* __restrict__ rbuf,
               const float* __restrict__ td, const float* __restrict__ tf,
               const float* __restrict__ tdr, const float* __restrict__ tfr,
               const float* __restrict__ cN, const float* __restrict__ cD,
               const float* __restrict__ cM) {
  const int bd = blockIdx.x;
  const int ch = blockIdx.y * 2 + threadIdx.y;
  const int dir = bd & 1;
  const int c = threadIdx.x * 8;
  const float* tdp = (dir ? tdr : td) + c;
  const float* tup = (dir ? tfr : tf) + c;
  const size_t ci = ((size_t)bd * NCH2 + ch) * CCH + c;
  float w[8], u[8], num[8], den[8], m[8];
  #pragma unroll
  for (int e = 0; e < 8; ++e) {
    w[e] = -__expf(tdp[e]); u[e] = tup[e];
    num[e] = cN[ci + e]; den[e] = cD[ci + e]; m[e] = cM[ci + e];
  }
  const size_t base = ((size_t)bd * TT + (size_t)ch * CHL2) * CCH + c;
  const _Float16* kp = kbuf + base;
  const _Float16* vp = vbuf + base;
  _Float16* rp = rbuf + base;
  h8 ka = *(const h8*)(kp), va = *(const h8*)(vp), ra = *(const h8*)(rp);
  h8 kb = *(const h8*)(kp + CCH), vb = *(const h8*)(vp + CCH), rb = *(const h8*)(rp + CCH);
  for (int t = 0; t < CHL2; ++t) {
    h8 kc = {}, vc = {}, rc = {};
    if (t + 2 < CHL2) {
      kc = *(const h8*)(kp + (size_t)(t + 2) * CCH);
      vc = *(const h8*)(vp + (size_t)(t + 2) * CCH);
      rc = *(const h8*)(rp + (size_t)(t + 2) * CCH);
    }
    _Float16 o[8];
    #pragma unroll
    for (int e = 0; e < 8; ++e) {
      float ke = (float)ka[e], ve = (float)va[e];
      float ku = ke + u[e];
      float mm = fmaxf(m[e], ku);
      float e1 = __expf(m[e] - mm), e2 = __expf(ku - mm);
      float y = (e1 * num[e] + e2 * ve) * __builtin_amdgcn_rcpf(e1 * den[e] + e2);
      float rt = (float)ra[e];
      float sig = __builtin_amdgcn_rcpf(1.f + __expf(-rt));
      o[e] = (_Float16)(sig * y);
      float mw = m[e] + w[e];
      float m2 = fmaxf(mw, ke);
      float es1 = __expf(mw - m2), es2 = __expf(ke - m2);
      num[e] = es1 * num[e] + es2 * ve;
      den[e] = es1 * den[e] + es2;
      m[e] = m2;
    }
    h8 ov = { o[0], o[1], o[2], o[3], o[4], o[5], o[6], o[7] };
    *(h8*)(rp + (size_t)t * CCH) = ov;   // overwrite r with o in place
    ka = kb; va = vb; ra = rb; kb = kc; vb = vc; rb = rc;
  }
}

// ---------- launch ----------
extern "C" void kernel_launch(void* const* d_in, const int* in_sizes, int n_in,
                              void* d_out, int out_size, void* d_ws, size_t ws_size,
                              hipStream_t stream) {
  const float* x   = (const float*)d_in[0];
  const float* Wr  = (const float*)d_in[1];
  const float* Wo  = (const float*)d_in[2];
  const float* td  = (const float*)d_in[3];
  const float* tf  = (const float*)d_in[4];
  const float* tdr = (const float*)d_in[5];
  const float* tfr = (const float*)d_in[6];
  float* out = (float*)d_out;

  auto rnd = [](size_t b) { return (b + 255) & ~(size_t)255; };
  const size_t wBytes = rnd((size_t)3072 * 512 * 2) + rnd((size_t)512 * 1024 * 2);
  auto need = [&](int Bs) {
    size_t s = wBytes;
    s += 3 * rnd((size_t)Bs * 2 * TT * 512 * 2);
    s += rnd((size_t)Bs * TT * 512 * 2);
    return s;
  };
  int Bs = 8;
  while (Bs > 1 && need(Bs) > ws_size) Bs >>= 1;

  char* ws = (char*)d_ws;
  size_t off = 0;
  auto alloc = [&](size_t bytes) -> char* {
    char* p = ws + off;
    off += (bytes + 255) & ~(size_t)255;
    return p;
  };
  unsigned short* wrkvT = (unsigned short*)alloc((size_t)3072 * 512 * 2);
  _Float16*       woutT = (_Float16*)alloc((size_t)512 * 1024 * 2);
  _Float16*       kbuf  = (_Float16*)alloc((size_t)Bs * 2 * TT * 512 * 2);
  _Float16*       vbuf  = (_Float16*)alloc((size_t)Bs * 2 * TT * 512 * 2);
  _Float16*       rbuf  = (_Float16*)alloc((size_t)Bs * 2 * TT * 512 * 2);
  unsigned short* xb    = (unsigned short*)alloc((size_t)Bs * TT * 512 * 2);
  // carries live inside xb (xb is dead after GEMM1 reads it)
  const size_t cs = (size_t)Bs * 2 * NCH2 * 512;
  const size_t ss = (size_t)Bs * 2 * NSEG * 512;
  float* cN  = (float*)xb;
  float* cD  = cN + cs;
  float* cM  = cD + cs;
  float* scN = cM + cs;
  float* scD = scN + ss;
  float* scM = scD + ss;

  transpose_to_bf16<<<dim3(3072 / 32, 512 / 32), dim3(32, 8), 0, stream>>>(Wr, wrkvT, 512, 3072);
  transpose_to_f16<<<dim3(512 / 32, 1024 / 32), dim3(32, 8), 0, stream>>>(Wo, woutT, 1024, 512);

  const int nslices = 8 / Bs;
  const int Mslice = Bs * TT;
  const int mt256 = Mslice >> 8;
  for (int s = 0; s < nslices; ++s) {
    const float* xs = x + (size_t)s * Mslice * 512;
    float* outs = out + (size_t)s * Mslice * 512;
    // 1. convert x slice to bf16 (into xb)
    convert_f32_bf16<<<Mslice * 512 / 1024, 256, 0, stream>>>(xs, xb, Mslice * 512 / 4);
    // 2. GEMM1 (256^2 pipelined): rkv = x @ W_rkv -> k/v/r (f16), bwd pre-reversed
    gemm256_g1<<<mt256 * 12, 512, 0, stream>>>(xb, wrkvT, kbuf, vbuf, rbuf);
    // 3. WKV chunked scan (carries overwrite xb region — xb is dead now)
    wkv_pass1<<<dim3(Bs * 2, NCH2 / 2), dim3(64, 2), 0, stream>>>(kbuf, vbuf, td, tdr, cN, cD, cM);
    wkv_p2a<<<dim3(Bs * 2, NSEG), 128, 0, stream>>>(td, tdr, cN, cD, cM, scN, scD, scM);
    wkv_p2b<<<Bs * 2, 128, 0, stream>>>(td, tdr, scN, scD, scM);
    wkv_p2c<<<dim3(Bs * 2, NSEG), 128, 0, stream>>>(td, tdr, scN, scD, scM, cN, cD, cM);
    wkv_pass3<<<dim3(Bs * 2, NCH2 / 2), dim3(64, 2), 0, stream>>>(kbuf, vbuf, rbuf, td, tf, tdr, tfr,
                                                                  cN, cD, cM);
    // 4. GEMM2 (256^2 pipelined, f16, two-half A): out = [oF | oB(rev)] @ W_out
    gemm2_256<<<mt256 * 2, 512, 0, stream>>>(rbuf, woutT, outs);
  }
}